// Round 1
// 592.825 us; speedup vs baseline: 1.1109x; 1.1109x over previous
//
#include <hip/hip_runtime.h>
#include <math.h>

#define D_MODEL 1024
#define TT 4096
#define NB 4
#define NH 16
#define NCH 16

typedef __attribute__((ext_vector_type(8))) short s8v;
typedef __attribute__((ext_vector_type(4))) float f4v;
typedef __attribute__((ext_vector_type(8))) unsigned short u16x8;

// ---- workspace layout (bytes); peak 80 MB (proven budget was 100 MB) ----
#define OFF_STATS ((size_t)0)
#define OFF_G     ((size_t)(1 << 20))
#define OFF_MM    (OFF_G + (size_t)(256 << 10))
#define OFF_CV    (OFF_MM + (size_t)(256 << 10))
#define OFF_FT    ((size_t)(2 << 20))
#define OFF_WKH   ((size_t)(4 << 20))
#define OFF_WKL   ((size_t)(5 << 20))
#define OFF_WQH   ((size_t)(6 << 20))
#define OFF_WQL   ((size_t)(7 << 20))
#define OFF_WVH   ((size_t)(8 << 20))
#define OFF_WVL   ((size_t)(10 << 20))
#define OFF_WOH   ((size_t)(12 << 20))
#define OFF_WOL   ((size_t)(14 << 20))
#define OFF_Y1    ((size_t)(16 << 20))
#define OFF_Y2    ((size_t)(48 << 20))   // 32 MB; full_hi overlays after build_gmc
#define OFF_FH    OFF_Y2

__device__ __forceinline__ unsigned short bf16_rne(float x) {
  unsigned u = __float_as_uint(x);
  return (unsigned short)((u + 0x7fffu + ((u >> 16) & 1u)) >> 16);
}
__device__ __forceinline__ void split_bf16(float x, unsigned short& h, unsigned short& l) {
  unsigned u = __float_as_uint(x);
  unsigned r = (u + 0x7fffu + ((u >> 16) & 1u)) & 0xffff0000u;
  h = (unsigned short)(r >> 16);
  float res = x - __uint_as_float(r);
  l = bf16_rne(res);
}

// ---------------- LayerNorm statistics: one block per row ----------------
__global__ __launch_bounds__(256) void ln_stats_k(const float* __restrict__ X,
                                                  float* __restrict__ stats) {
  int r = blockIdx.x;
  const float4 v = ((const float4*)(X + (size_t)r * D_MODEL))[threadIdx.x];
  float s  = v.x + v.y + v.z + v.w;
  float ss = v.x * v.x + v.y * v.y + v.z * v.z + v.w * v.w;
#pragma unroll
  for (int off = 32; off > 0; off >>= 1) {
    s  += __shfl_down(s, off, 64);
    ss += __shfl_down(ss, off, 64);
  }
  __shared__ float as_[4], bs_[4];
  int w = threadIdx.x >> 6, lane = threadIdx.x & 63;
  if (lane == 0) { as_[w] = s; bs_[w] = ss; }
  __syncthreads();
  if (threadIdx.x == 0) {
    float S  = as_[0] + as_[1] + as_[2] + as_[3];
    float SS = bs_[0] + bs_[1] + bs_[2] + bs_[3];
    float mu  = S * (1.0f / D_MODEL);
    float var = SS * (1.0f / D_MODEL) - mu * mu;
    stats[2 * (size_t)r]     = mu;
    stats[2 * (size_t)r + 1] = 1.0f / sqrtf(var + 1e-5f);
  }
}

// ------- prep: transpose W[K][N] -> WT_hi/lo [N][K] bf16 split -------
__global__ __launch_bounds__(256) void prep_w_k(const float* __restrict__ W, int N,
                                                unsigned short* __restrict__ Thi,
                                                unsigned short* __restrict__ Tlo) {
  __shared__ float tileT[32 * 33];
  const int n0 = blockIdx.x * 32, k0 = blockIdx.y * 32;
  const int tid = threadIdx.x;
  {
    int k_l = tid >> 3, n4 = (tid & 7) << 2;
    float4 v = *(const float4*)&W[(size_t)(k0 + k_l) * N + n0 + n4];
    tileT[(n4 + 0) * 33 + k_l] = v.x;
    tileT[(n4 + 1) * 33 + k_l] = v.y;
    tileT[(n4 + 2) * 33 + k_l] = v.z;
    tileT[(n4 + 3) * 33 + k_l] = v.w;
  }
  __syncthreads();
  {
    int n_l = tid >> 3, k4 = (tid & 7) << 2;
    unsigned short h[4], l[4];
#pragma unroll
    for (int i = 0; i < 4; i++) split_bf16(tileT[n_l * 33 + k4 + i], h[i], l[i]);
    *(ushort4*)&Thi[(size_t)(n0 + n_l) * 1024 + k0 + k4] = make_ushort4(h[0], h[1], h[2], h[3]);
    *(ushort4*)&Tlo[(size_t)(n0 + n_l) * 1024 + k0 + k4] = make_ushort4(l[0], l[1], l[2], l[3]);
  }
}

// ------- fused LN + projection GEMM, split-bf16 MFMA (3 products) -------
// mode 0: rows t<P, Wk -> Y1 ; mode 1: rows t>=P, Wq -> Y1 ; mode 2: rows t<P, Wv -> Y2 compact
__global__ __launch_bounds__(256) void gemm_proj_k(
    const float* __restrict__ X, const float* __restrict__ stats,
    const float* __restrict__ lng, const float* __restrict__ lnb,
    const unsigned short* __restrict__ WThi, const unsigned short* __restrict__ WTlo,
    int Nw, const int* __restrict__ pref, int mode, float* __restrict__ Y) {
  int P = pref[0]; P = P < 1 ? 1 : (P > TT - 1 ? TT - 1 : P);
  const int b  = blockIdx.z;
  const int t0 = blockIdx.y * 128;
  const int n0 = blockIdx.x * 128;
  if (mode == 1) { if (t0 + 128 <= P) return; }
  else           { if (t0 >= P) return; }
  const int row0 = b * TT + t0;
  __shared__ __align__(16) unsigned short Ah[128 * 40], Al[128 * 40];
  __shared__ __align__(16) unsigned short Bh[128 * 40], Bl[128 * 40];
  __shared__ float mus[128], rss[128];
  const int tid = threadIdx.x;
  if (tid < 128) {
    mus[tid] = stats[2 * (size_t)(row0 + tid)];
    rss[tid] = stats[2 * (size_t)(row0 + tid) + 1];
  }
  const int lane = tid & 63;
  const int wm = ((tid >> 6) >> 1) * 64, wn = ((tid >> 6) & 1) * 64;
  const int lm = lane & 15, lq = lane >> 4;
  f4v acc[4][4];
#pragma unroll
  for (int i = 0; i < 4; i++)
#pragma unroll
    for (int j = 0; j < 4; j++) acc[i][j] = (f4v){0.f, 0.f, 0.f, 0.f};

  for (int kt = 0; kt < D_MODEL; kt += 32) {
    __syncthreads();
#pragma unroll
    for (int q = 0; q < 2; q++) {
      int c = tid * 2 + q;
      int m = c >> 2, k8 = (c & 3) << 3;
      const float* src = &X[(size_t)(row0 + m) * D_MODEL + kt + k8];
      float mu = mus[m], rs = rss[m];
      u16x8 hv, lv;
#pragma unroll
      for (int i = 0; i < 8; i++) {
        float nv = (src[i] - mu) * rs * lng[kt + k8 + i] + lnb[kt + k8 + i];
        unsigned short h, l;
        split_bf16(nv, h, l);
        hv[i] = h; lv[i] = l;
      }
      *(u16x8*)&Ah[m * 40 + k8] = hv;
      *(u16x8*)&Al[m * 40 + k8] = lv;
      *(u16x8*)&Bh[m * 40 + k8] = *(const u16x8*)&WThi[(size_t)(n0 + m) * 1024 + kt + k8];
      *(u16x8*)&Bl[m * 40 + k8] = *(const u16x8*)&WTlo[(size_t)(n0 + m) * 1024 + kt + k8];
    }
    __syncthreads();
    s8v ah[4], al[4], bh[4], bl[4];
#pragma unroll
    for (int i = 0; i < 4; i++) {
      int ar = (wm + i * 16 + lm) * 40 + lq * 8;
      int br = (wn + i * 16 + lm) * 40 + lq * 8;
      ah[i] = *(const s8v*)&Ah[ar];
      al[i] = *(const s8v*)&Al[ar];
      bh[i] = *(const s8v*)&Bh[br];
      bl[i] = *(const s8v*)&Bl[br];
    }
#pragma unroll
    for (int mi = 0; mi < 4; mi++)
#pragma unroll
      for (int ni = 0; ni < 4; ni++) {
        acc[mi][ni] = __builtin_amdgcn_mfma_f32_16x16x32_bf16(ah[mi], bh[ni], acc[mi][ni], 0, 0, 0);
        acc[mi][ni] = __builtin_amdgcn_mfma_f32_16x16x32_bf16(ah[mi], bl[ni], acc[mi][ni], 0, 0, 0);
        acc[mi][ni] = __builtin_amdgcn_mfma_f32_16x16x32_bf16(al[mi], bh[ni], acc[mi][ni], 0, 0, 0);
      }
  }
#pragma unroll
  for (int mi = 0; mi < 4; mi++) {
#pragma unroll
    for (int r = 0; r < 4; r++) {
      int t = t0 + wm + mi * 16 + lq * 4 + r;
      bool ok = (mode == 1) ? (t >= P) : (t < P);
      if (!ok) continue;
      size_t orow = (mode == 2) ? ((size_t)b * P + t) : ((size_t)b * TT + t);
#pragma unroll
      for (int ni = 0; ni < 4; ni++)
        Y[orow * Nw + n0 + wn + ni * 16 + lm] = acc[mi][ni][r];
    }
  }
}

// ------- merged K/Q projection: one launch, all t-blocks active (2 blocks/CU) -------
// rows t<P get Wk, rows t>=P get Wq; straddling tile runs both passes row-masked.
__global__ __launch_bounds__(256) void gemm_kq_k(
    const float* __restrict__ X, const float* __restrict__ stats,
    const float* __restrict__ lng, const float* __restrict__ lnb,
    const unsigned short* __restrict__ KH, const unsigned short* __restrict__ KL,
    const unsigned short* __restrict__ QH, const unsigned short* __restrict__ QL,
    const int* __restrict__ pref, float* __restrict__ Y) {
  int P = pref[0]; P = P < 1 ? 1 : (P > TT - 1 ? TT - 1 : P);
  const int b  = blockIdx.z;
  const int t0 = blockIdx.y * 128;
  const int n0 = blockIdx.x * 128;
  const int row0 = b * TT + t0;
  const bool hasK = (t0 < P);
  const bool hasQ = (t0 + 128 > P);
  __shared__ __align__(16) unsigned short Ah[128 * 40], Al[128 * 40];
  __shared__ __align__(16) unsigned short Bh[128 * 40], Bl[128 * 40];
  __shared__ float mus[128], rss[128];
  const int tid = threadIdx.x;
  if (tid < 128) {
    mus[tid] = stats[2 * (size_t)(row0 + tid)];
    rss[tid] = stats[2 * (size_t)(row0 + tid) + 1];
  }
  const int lane = tid & 63;
  const int wm = ((tid >> 6) >> 1) * 64, wn = ((tid >> 6) & 1) * 64;
  const int lm = lane & 15, lq = lane >> 4;

  for (int pass = 0; pass < 2; pass++) {
    if (pass == 0 && !hasK) continue;
    if (pass == 1 && !hasQ) continue;
    const unsigned short* WThi = pass ? QH : KH;
    const unsigned short* WTlo = pass ? QL : KL;
    f4v acc[4][4];
#pragma unroll
    for (int i = 0; i < 4; i++)
#pragma unroll
      for (int j = 0; j < 4; j++) acc[i][j] = (f4v){0.f, 0.f, 0.f, 0.f};

    for (int kt = 0; kt < D_MODEL; kt += 32) {
      __syncthreads();
#pragma unroll
      for (int q = 0; q < 2; q++) {
        int c = tid * 2 + q;
        int m = c >> 2, k8 = (c & 3) << 3;
        const float* src = &X[(size_t)(row0 + m) * D_MODEL + kt + k8];
        float mu = mus[m], rs = rss[m];
        u16x8 hv, lv;
#pragma unroll
        for (int i = 0; i < 8; i++) {
          float nv = (src[i] - mu) * rs * lng[kt + k8 + i] + lnb[kt + k8 + i];
          unsigned short h, l;
          split_bf16(nv, h, l);
          hv[i] = h; lv[i] = l;
        }
        *(u16x8*)&Ah[m * 40 + k8] = hv;
        *(u16x8*)&Al[m * 40 + k8] = lv;
        *(u16x8*)&Bh[m * 40 + k8] = *(const u16x8*)&WThi[(size_t)(n0 + m) * 1024 + kt + k8];
        *(u16x8*)&Bl[m * 40 + k8] = *(const u16x8*)&WTlo[(size_t)(n0 + m) * 1024 + kt + k8];
      }
      __syncthreads();
      s8v ah[4], al[4], bh[4], bl[4];
#pragma unroll
      for (int i = 0; i < 4; i++) {
        int ar = (wm + i * 16 + lm) * 40 + lq * 8;
        int br = (wn + i * 16 + lm) * 40 + lq * 8;
        ah[i] = *(const s8v*)&Ah[ar];
        al[i] = *(const s8v*)&Al[ar];
        bh[i] = *(const s8v*)&Bh[br];
        bl[i] = *(const s8v*)&Bl[br];
      }
#pragma unroll
      for (int mi = 0; mi < 4; mi++)
#pragma unroll
        for (int ni = 0; ni < 4; ni++) {
          acc[mi][ni] = __builtin_amdgcn_mfma_f32_16x16x32_bf16(ah[mi], bh[ni], acc[mi][ni], 0, 0, 0);
          acc[mi][ni] = __builtin_amdgcn_mfma_f32_16x16x32_bf16(ah[mi], bl[ni], acc[mi][ni], 0, 0, 0);
          acc[mi][ni] = __builtin_amdgcn_mfma_f32_16x16x32_bf16(al[mi], bh[ni], acc[mi][ni], 0, 0, 0);
        }
    }
#pragma unroll
    for (int mi = 0; mi < 4; mi++) {
#pragma unroll
      for (int r = 0; r < 4; r++) {
        int t = t0 + wm + mi * 16 + lq * 4 + r;
        bool ok = pass ? (t >= P) : (t < P);
        if (!ok) continue;
#pragma unroll
        for (int ni = 0; ni < 4; ni++)
          Y[((size_t)b * TT + t) * 512 + n0 + wn + ni * 16 + lm] = acc[mi][ni][r];
      }
    }
  }
}

// ------------- G, M, C_v Gram reductions (atomic accumulate) -------------
__global__ __launch_bounds__(256) void build_gmc_k(
    const float* __restrict__ Y1, const float* __restrict__ Y2,
    const int* __restrict__ pref,
    float* __restrict__ G, float* __restrict__ Mm, float* __restrict__ Cv) {
  int P = pref[0]; P = P < 1 ? 1 : (P > TT - 1 ? TT - 1 : P);
  const int bh = blockIdx.y;
  const int b = bh >> 4, h = bh & 15;
  const int tid = threadIdx.x;
  const int chunk = (P + NCH - 1) / NCH;
  const int tb = blockIdx.x * chunk;
  const int te = min(tb + chunk, P);
  if (tb >= te) return;
  __shared__ float kt[129 * 32];
  __shared__ float vt[128 * 64];
  float aG[4] = {}, aM[4] = {}, aC[8] = {};
  const int ii = tid >> 3, j4 = (tid & 7) << 2;
  const int dd = tid >> 2, j8 = (tid & 3) << 3;
  for (int t0 = tb; t0 < te; t0 += 128) {
    const int len = min(128, te - t0);
    __syncthreads();
    for (int e = tid; e < (len + 1) * 8; e += 256) {
      int row = e >> 3, jj = (e & 7) << 2;
      int t = t0 - 1 + row;
      float4 v = make_float4(0.f, 0.f, 0.f, 0.f);
      if (t >= 0) v = *(const float4*)&Y1[((size_t)b * TT + t) * 512 + h * 32 + jj];
      *(float4*)&kt[row * 32 + jj] = v;
    }
    for (int e = tid; e < len * 16; e += 256) {
      int row = e >> 4, dj = (e & 15) << 2;
      int t = t0 + row;
      *(float4*)&vt[row * 64 + dj] =
          *(const float4*)&Y2[((size_t)b * P + t) * 1024 + h * 64 + dj];
    }
    __syncthreads();
    for (int s = 0; s < len; s++) {
      float ki  = kt[(s + 1) * 32 + ii];
      float4 kj = *(const float4*)&kt[(s + 1) * 32 + j4];
      float4 km = *(const float4*)&kt[s * 32 + j4];
      aG[0] += ki * kj.x; aG[1] += ki * kj.y; aG[2] += ki * kj.z; aG[3] += ki * kj.w;
      aM[0] += ki * km.x; aM[1] += ki * km.y; aM[2] += ki * km.z; aM[3] += ki * km.w;
      float vd  = vt[s * 64 + dd];
      float4 ka = *(const float4*)&kt[(s + 1) * 32 + j8];
      float4 kb = *(const float4*)&kt[(s + 1) * 32 + j8 + 4];
      aC[0] += vd * ka.x; aC[1] += vd * ka.y; aC[2] += vd * ka.z; aC[3] += vd * ka.w;
      aC[4] += vd * kb.x; aC[5] += vd * kb.y; aC[6] += vd * kb.z; aC[7] += vd * kb.w;
    }
  }
  float* Gd = &G[(size_t)bh * 1024 + ii * 32 + j4];
  atomicAdd(&Gd[0], aG[0]); atomicAdd(&Gd[1], aG[1]);
  atomicAdd(&Gd[2], aG[2]); atomicAdd(&Gd[3], aG[3]);
  float* Md = &Mm[(size_t)bh * 1024 + ii * 32 + j4];
  atomicAdd(&Md[0], aM[0]); atomicAdd(&Md[1], aM[1]);
  atomicAdd(&Md[2], aM[2]); atomicAdd(&Md[3], aM[3]);
  float* Cd = &Cv[(size_t)bh * 2048 + dd * 32 + j8];
#pragma unroll
  for (int q = 0; q < 8; q++) atomicAdd(&Cd[q], aC[q]);
}

// ------- per-(b,h) operator: chol, G^{-1}, A_w, sigma, F = Cv*Gi*(s*M*Gi)^4 -------
__global__ __launch_bounds__(256) void solve_op_k(
    const float* __restrict__ G, const float* __restrict__ Mm,
    const float* __restrict__ Cv, const float* __restrict__ lridge,
    const float* __restrict__ lgamma, float* __restrict__ Ft) {
  __shared__ float Gs[32 * 33];
  __shared__ float Ms[32 * 32];
  __shared__ float Gi[32 * 32];
  __shared__ float W1[32 * 33];
  __shared__ float Aw[32 * 33];
  __shared__ float Nn[32 * 32];
  __shared__ float N2[32 * 32];
  __shared__ float T1[32 * 32];
  __shared__ float Cs[64 * 32];
  __shared__ float red[256];
  __shared__ float vv[32], uu[32];
  const int bh = blockIdx.x;
  const int tid = threadIdx.x;
  const float ridge = expf(lridge[0]);

  for (int e = tid; e < 1024; e += 256) {
    int i = e >> 5, j = e & 31;
    float g = G[(size_t)bh * 1024 + e];
    if (i == j) g += ridge;
    Gs[i * 33 + j] = g;
    Ms[e] = Mm[(size_t)bh * 1024 + e];
  }
  for (int e = tid; e < 2048; e += 256) Cs[e] = Cv[(size_t)bh * 2048 + e];
  __syncthreads();

  for (int j = 0; j < 32; j++) {
    float d = Gs[j * 33 + j];
    __syncthreads();
    float inv = 1.0f / sqrtf(d);
    if (tid >= j && tid < 32) Gs[tid * 33 + j] *= inv;
    __syncthreads();
    int w = 31 - j;
    for (int e = tid; e < w * w; e += 256) {
      int i = j + 1 + e / w, k = j + 1 + e % w;
      Gs[i * 33 + k] -= Gs[i * 33 + j] * Gs[k * 33 + j];
    }
    __syncthreads();
  }

  if (tid < 32) {
    const int c = tid;
    for (int i = 0; i < 32; i++) W1[i * 33 + c] = (i == c) ? 1.0f : 0.0f;
    for (int i = 0; i < 32; i++) {
      float s = W1[i * 33 + c];
      for (int j = 0; j < i; j++) s -= Gs[i * 33 + j] * W1[j * 33 + c];
      W1[i * 33 + c] = s / Gs[i * 33 + i];
    }
    for (int i = 31; i >= 0; i--) {
      float s = W1[i * 33 + c];
      for (int j = i + 1; j < 32; j++) s -= Gs[j * 33 + i] * W1[j * 33 + c];
      W1[i * 33 + c] = s / Gs[i * 33 + i];
    }
    for (int i = 0; i < 32; i++) Gi[i * 32 + c] = W1[i * 33 + c];
  }
  __syncthreads();
  if (tid < 32) {
    const int c = tid;
    for (int i = 0; i < 32; i++) {
      float s = Ms[i * 32 + c];
      for (int j = 0; j < i; j++) s -= Gs[i * 33 + j] * W1[j * 33 + c];
      W1[i * 33 + c] = s / Gs[i * 33 + i];
    }
  }
  __syncthreads();
  if (tid < 32) {
    const int c = tid;
    for (int i = 0; i < 32; i++) {
      float s = W1[c * 33 + i];
      for (int j = 0; j < i; j++) s -= Gs[i * 33 + j] * Aw[j * 33 + c];
      Aw[i * 33 + c] = s / Gs[i * 33 + i];
    }
  }
  __syncthreads();

  float s0 = 0.0f;
  for (int e = tid; e < 1024; e += 256) {
    float a = Aw[(e >> 5) * 33 + (e & 31)];
    s0 += a * a;
  }
  red[tid] = s0;
  __syncthreads();
  for (int off = 128; off > 0; off >>= 1) {
    if (tid < off) red[tid] += red[tid + off];
    __syncthreads();
  }
  float frob2 = red[0];
  float sigma;
  if (frob2 <= 1.0f) {
    sigma = sqrtf(frob2);
  } else {
    if (tid < 32) vv[tid] = 1.0f + 0.001f * (float)tid;
    __syncthreads();
    for (int it = 0; it < 64; it++) {
      if (tid < 32) {
        float s = 0;
        for (int j = 0; j < 32; j++) s += Aw[tid * 33 + j] * vv[j];
        uu[tid] = s;
      }
      __syncthreads();
      if (tid == 0) {
        float n = 0;
        for (int j = 0; j < 32; j++) n += uu[j] * uu[j];
        red[0] = sqrtf(n);
      }
      __syncthreads();
      float nu = fmaxf(red[0], 1e-30f);
      if (tid < 32) uu[tid] /= nu;
      __syncthreads();
      if (tid < 32) {
        float s = 0;
        for (int j = 0; j < 32; j++) s += Aw[j * 33 + tid] * uu[j];
        vv[tid] = s;
      }
      __syncthreads();
      if (tid == 0) {
        float n = 0;
        for (int j = 0; j < 32; j++) n += vv[j] * vv[j];
        red[0] = sqrtf(n);
      }
      __syncthreads();
      float nv = fmaxf(red[0], 1e-30f);
      if (tid < 32) vv[tid] /= nv;
      __syncthreads();
    }
    sigma = red[0];
  }
  float gamma_c = fminf(expf(lgamma[0]), 1.0f);
  float scale = gamma_c / fmaxf(fmaxf(sigma, 1e-8f), 1.0f);

  for (int e = tid; e < 1024; e += 256) {
    int i = e >> 5, c = e & 31;
    float s = 0;
#pragma unroll
    for (int k = 0; k < 32; k++) s += Ms[i * 32 + k] * Gi[k * 32 + c];
    Nn[e] = scale * s;
  }
  __syncthreads();
  for (int e = tid; e < 1024; e += 256) {
    int i = e >> 5, c = e & 31;
    float s = 0;
#pragma unroll
    for (int k = 0; k < 32; k++) s += Nn[i * 32 + k] * Nn[k * 32 + c];
    N2[e] = s;
  }
  __syncthreads();
  for (int e = tid; e < 1024; e += 256) {
    int i = e >> 5, c = e & 31;
    float s = 0;
#pragma unroll
    for (int k = 0; k < 32; k++) s += N2[i * 32 + k] * N2[k * 32 + c];
    Ms[e] = s;
  }
  __syncthreads();
  for (int e = tid; e < 1024; e += 256) {
    int i = e >> 5, c = e & 31;
    float s = 0;
#pragma unroll
    for (int k = 0; k < 32; k++) s += Gi[i * 32 + k] * Ms[k * 32 + c];
    T1[e] = s;
  }
  __syncthreads();
  for (int e = tid; e < 2048; e += 256) {
    int j = e >> 6, d = e & 63;
    float s = 0;
#pragma unroll
    for (int k = 0; k < 32; k++) s += Cs[d * 32 + k] * T1[k * 32 + j];
    Ft[(size_t)bh * 2048 + e] = s;
  }
}

// ------------- apply F^T per (head, 128-token chunk) -> full_hi (bf16) -------------
// F-column for each thread's fixed d is loop-invariant -> registers (global load,
// Ft is L2-resident). xs reads are wave-uniform broadcasts (conflict-free b128).
__global__ __launch_bounds__(256) void apply_k(const float* __restrict__ Y1,
                                               const float* __restrict__ Ft,
                                               unsigned short* __restrict__ FH) {
  __shared__ float xs[128 * 32];
  const int h = blockIdx.y;
  const int r0 = blockIdx.x * 128;
  const int bh = (r0 >> 12) * NH + h;
  const int tid = threadIdx.x;
  const int d = tid & 63, t0 = tid >> 6;
  float fcol[32];
  const float* fb = &Ft[(size_t)bh * 2048 + d];
#pragma unroll
  for (int j = 0; j < 32; j++) fcol[j] = fb[j * 64];
  for (int e = tid; e < 1024; e += 256) {
    int row = e >> 3, j4 = (e & 7) << 2;
    *(float4*)&xs[row * 32 + j4] =
        *(const float4*)&Y1[((size_t)(r0 + row)) * 512 + h * 32 + j4];
  }
  __syncthreads();
  for (int tl = t0; tl < 128; tl += 4) {
    float s = 0;
#pragma unroll
    for (int j = 0; j < 32; j++) s += xs[tl * 32 + j] * fcol[j];
    FH[((size_t)(r0 + tl)) * 1024 + h * 64 + d] = bf16_rne(s);
  }
}

// ------------- output GEMM (MFMA): out = sg * full @ Wo ; A=hi, B=hi+lo -------------
__global__ __launch_bounds__(256) void gemm_out_k(
    const unsigned short* __restrict__ FH,
    const unsigned short* __restrict__ WThi, const unsigned short* __restrict__ WTlo,
    const float* __restrict__ alpha, float* __restrict__ out) {
  const int m0 = blockIdx.y * 128;
  const int n0 = blockIdx.x * 128;
  __shared__ __align__(16) unsigned short Ah[128 * 40];
  __shared__ __align__(16) unsigned short Bh[128 * 40], Bl[128 * 40];
  const int tid = threadIdx.x;
  const int lane = tid & 63;
  const int wm = ((tid >> 6) >> 1) * 64, wn = ((tid >> 6) & 1) * 64;
  const int lm = lane & 15, lq = lane >> 4;
  f4v acc[4][4];
#pragma unroll
  for (int i = 0; i < 4; i++)
#pragma unroll
    for (int j = 0; j < 4; j++) acc[i][j] = (f4v){0.f, 0.f, 0.f, 0.f};

  for (int kt = 0; kt < D_MODEL; kt += 32) {
    __syncthreads();
#pragma unroll
    for (int q = 0; q < 2; q++) {
      int c = tid * 2 + q;
      int m = c >> 2, k8 = (c & 3) << 3;
      *(u16x8*)&Ah[m * 40 + k8] = *(const u16x8*)&FH[(size_t)(m0 + m) * 1024 + kt + k8];
      *(u16x8*)&Bh[m * 40 + k8] = *(const u16x8*)&WThi[(size_t)(n0 + m) * 1024 + kt + k8];
      *(u16x8*)&Bl[m * 40 + k8] = *(const u16x8*)&WTlo[(size_t)(n0 + m) * 1024 + kt + k8];
    }
    __syncthreads();
    s8v ah[4], bh[4], bl[4];
#pragma unroll
    for (int i = 0; i < 4; i++) {
      ah[i] = *(const s8v*)&Ah[(wm + i * 16 + lm) * 40 + lq * 8];
      bh[i] = *(const s8v*)&Bh[(wn + i * 16 + lm) * 40 + lq * 8];
      bl[i] = *(const s8v*)&Bl[(wn + i * 16 + lm) * 40 + lq * 8];
    }
#pragma unroll
    for (int mi = 0; mi < 4; mi++)
#pragma unroll
      for (int ni = 0; ni < 4; ni++) {
        acc[mi][ni] = __builtin_amdgcn_mfma_f32_16x16x32_bf16(ah[mi], bh[ni], acc[mi][ni], 0, 0, 0);
        acc[mi][ni] = __builtin_amdgcn_mfma_f32_16x16x32_bf16(ah[mi], bl[ni], acc[mi][ni], 0, 0, 0);
      }
  }
  float sg = 1.0f / (1.0f + expf(-alpha[0]));
#pragma unroll
  for (int mi = 0; mi < 4; mi++)
#pragma unroll
    for (int r = 0; r < 4; r++) {
      size_t orow = (size_t)(m0 + wm + mi * 16 + lq * 4 + r);
#pragma unroll
      for (int ni = 0; ni < 4; ni++)
        out[orow * 1024 + n0 + wn + ni * 16 + lm] = sg * acc[mi][ni][r];
    }
}

extern "C" void kernel_launch(void* const* d_in, const int* in_sizes, int n_in,
                              void* d_out, int out_size, void* d_ws, size_t ws_size,
                              hipStream_t stream) {
  const float* X      = (const float*)d_in[0];
  const float* Wk     = (const float*)d_in[1];
  const float* Wq     = (const float*)d_in[2];
  const float* Wv     = (const float*)d_in[3];
  const float* Wo     = (const float*)d_in[4];
  const float* lng    = (const float*)d_in[5];
  const float* lnb    = (const float*)d_in[6];
  const float* alpha  = (const float*)d_in[7];
  const float* lridge = (const float*)d_in[8];
  const float* lgamma = (const float*)d_in[9];
  const int*   pref   = (const int*)d_in[10];
  float* out = (float*)d_out;
  char* ws = (char*)d_ws;
  float* stats = (float*)(ws + OFF_STATS);
  float* G     = (float*)(ws + OFF_G);
  float* Mm    = (float*)(ws + OFF_MM);
  float* Cv    = (float*)(ws + OFF_CV);
  float* Ft    = (float*)(ws + OFF_FT);
  unsigned short* WKH = (unsigned short*)(ws + OFF_WKH);
  unsigned short* WKL = (unsigned short*)(ws + OFF_WKL);
  unsigned short* WQH = (unsigned short*)(ws + OFF_WQH);
  unsigned short* WQL = (unsigned short*)(ws + OFF_WQL);
  unsigned short* WVH = (unsigned short*)(ws + OFF_WVH);
  unsigned short* WVL = (unsigned short*)(ws + OFF_WVL);
  unsigned short* WOH = (unsigned short*)(ws + OFF_WOH);
  unsigned short* WOL = (unsigned short*)(ws + OFF_WOL);
  float* Y1 = (float*)(ws + OFF_Y1);
  float* Y2 = (float*)(ws + OFF_Y2);
  unsigned short* FH = (unsigned short*)(ws + OFF_FH);

  hipMemsetAsync(ws + OFF_G, 0, 1 << 20, stream);
  ln_stats_k<<<16384, 256, 0, stream>>>(X, stats);
  prep_w_k<<<dim3(16, 32), 256, 0, stream>>>(Wk, 512, WKH, WKL);
  prep_w_k<<<dim3(16, 32), 256, 0, stream>>>(Wq, 512, WQH, WQL);
  prep_w_k<<<dim3(32, 32), 256, 0, stream>>>(Wv, 1024, WVH, WVL);
  prep_w_k<<<dim3(32, 32), 256, 0, stream>>>(Wo, 1024, WOH, WOL);
  gemm_kq_k<<<dim3(4, 32, NB), 256, 0, stream>>>(X, stats, lng, lnb, WKH, WKL, WQH, WQL, pref, Y1);
  gemm_proj_k<<<dim3(8, 32, NB), 256, 0, stream>>>(X, stats, lng, lnb, WVH, WVL, 1024, pref, 2, Y2);
  build_gmc_k<<<dim3(NCH, 64), 256, 0, stream>>>(Y1, Y2, pref, G, Mm, Cv);
  solve_op_k<<<64, 256, 0, stream>>>(G, Mm, Cv, lridge, lgamma, Ft);
  apply_k<<<dim3(128, NH), 256, 0, stream>>>(Y1, Ft, FH);
  gemm_out_k<<<dim3(8, 128), 256, 0, stream>>>(FH, WOH, WOL, alpha, out);
}

// Round 2
// 492.650 us; speedup vs baseline: 1.3367x; 1.2033x over previous
//
#include <hip/hip_runtime.h>
#include <math.h>

#define D_MODEL 1024
#define TT 4096
#define NB 4
#define NH 16
#define TCH 8

typedef __attribute__((ext_vector_type(8))) short s8v;
typedef __attribute__((ext_vector_type(4))) float f4v;
typedef __attribute__((ext_vector_type(8))) unsigned short u16x8;

// ---- workspace layout (bytes); peak ~88 MB (proven budget 100 MB) ----
#define OFF_STATS ((size_t)0)
#define OFF_GP    ((size_t)(1) << 20)    // 8*64*1024*4 = 2 MB partials
#define OFF_MP    ((size_t)(3) << 20)    // 2 MB
#define OFF_CP    ((size_t)(5) << 20)    // 8*64*2048*4 = 4 MB
#define OFF_FT    ((size_t)(9) << 20)    // 512 KB
#define OFF_WKH   ((size_t)(10) << 20)
#define OFF_WKL   ((size_t)(11) << 20)
#define OFF_WQH   ((size_t)(12) << 20)
#define OFF_WQL   ((size_t)(13) << 20)
#define OFF_WVH   ((size_t)(14) << 20)
#define OFF_WVL   ((size_t)(16) << 20)
#define OFF_WOH   ((size_t)(18) << 20)
#define OFF_WOL   ((size_t)(20) << 20)
#define OFF_Y1    ((size_t)(22) << 20)   // 32 MB
#define OFF_Y2    ((size_t)(54) << 20)   // P*NB*1024*4; FH overlays after build_gmc
#define OFF_FH    OFF_Y2

__device__ __forceinline__ unsigned short bf16_rne(float x) {
  unsigned u = __float_as_uint(x);
  return (unsigned short)((u + 0x7fffu + ((u >> 16) & 1u)) >> 16);
}
__device__ __forceinline__ void split_bf16(float x, unsigned short& h, unsigned short& l) {
  unsigned u = __float_as_uint(x);
  unsigned r = (u + 0x7fffu + ((u >> 16) & 1u)) & 0xffff0000u;
  h = (unsigned short)(r >> 16);
  float res = x - __uint_as_float(r);
  l = bf16_rne(res);
}

// bijective XCD swizzle: the gx blocks sharing one (y,z) land consecutively on ONE
// XCD; (y,z) values strided by 8 across XCDs (keeps P-masked kernels balanced).
__device__ __forceinline__ void xcd_swz(int gx, int gy, int& x, int& y, int& z) {
  int wg = blockIdx.x + gx * (blockIdx.y + gy * blockIdx.z);
  int k = wg & 7, j = wg >> 3;
  x = j % gx;
  int yz = k + ((j / gx) << 3);
  y = yz % gy;
  z = yz / gy;
}

// ---------------- LayerNorm statistics: one block per row ----------------
__global__ __launch_bounds__(256) void ln_stats_k(const float* __restrict__ X,
                                                  float* __restrict__ stats) {
  int r = blockIdx.x;
  const float4 v = ((const float4*)(X + (size_t)r * D_MODEL))[threadIdx.x];
  float s  = v.x + v.y + v.z + v.w;
  float ss = v.x * v.x + v.y * v.y + v.z * v.z + v.w * v.w;
#pragma unroll
  for (int off = 32; off > 0; off >>= 1) {
    s  += __shfl_down(s, off, 64);
    ss += __shfl_down(ss, off, 64);
  }
  __shared__ float as_[4], bs_[4];
  int w = threadIdx.x >> 6, lane = threadIdx.x & 63;
  if (lane == 0) { as_[w] = s; bs_[w] = ss; }
  __syncthreads();
  if (threadIdx.x == 0) {
    float S  = as_[0] + as_[1] + as_[2] + as_[3];
    float SS = bs_[0] + bs_[1] + bs_[2] + bs_[3];
    float mu  = S * (1.0f / D_MODEL);
    float var = SS * (1.0f / D_MODEL) - mu * mu;
    stats[2 * (size_t)r]     = mu;
    stats[2 * (size_t)r + 1] = 1.0f / sqrtf(var + 1e-5f);
  }
}

// ------- prep: transpose W[K][N] -> WT_hi/lo [N][K] bf16 split -------
__global__ __launch_bounds__(256) void prep_w_k(const float* __restrict__ W, int N,
                                                unsigned short* __restrict__ Thi,
                                                unsigned short* __restrict__ Tlo) {
  __shared__ float tileT[32 * 33];
  const int n0 = blockIdx.x * 32, k0 = blockIdx.y * 32;
  const int tid = threadIdx.x;
  {
    int k_l = tid >> 3, n4 = (tid & 7) << 2;
    float4 v = *(const float4*)&W[(size_t)(k0 + k_l) * N + n0 + n4];
    tileT[(n4 + 0) * 33 + k_l] = v.x;
    tileT[(n4 + 1) * 33 + k_l] = v.y;
    tileT[(n4 + 2) * 33 + k_l] = v.z;
    tileT[(n4 + 3) * 33 + k_l] = v.w;
  }
  __syncthreads();
  {
    int n_l = tid >> 3, k4 = (tid & 7) << 2;
    unsigned short h[4], l[4];
#pragma unroll
    for (int i = 0; i < 4; i++) split_bf16(tileT[n_l * 33 + k4 + i], h[i], l[i]);
    *(ushort4*)&Thi[(size_t)(n0 + n_l) * 1024 + k0 + k4] = make_ushort4(h[0], h[1], h[2], h[3]);
    *(ushort4*)&Tlo[(size_t)(n0 + n_l) * 1024 + k0 + k4] = make_ushort4(l[0], l[1], l[2], l[3]);
  }
}

// ------- fused LN + projection GEMM, split-bf16 MFMA (3 products) -------
// mode 2: rows t<P, Wv -> Y2 compact
__global__ __launch_bounds__(256) void gemm_proj_k(
    const float* __restrict__ X, const float* __restrict__ stats,
    const float* __restrict__ lng, const float* __restrict__ lnb,
    const unsigned short* __restrict__ WThi, const unsigned short* __restrict__ WTlo,
    int Nw, const int* __restrict__ pref, int mode, float* __restrict__ Y) {
  int P = pref[0]; P = P < 1 ? 1 : (P > TT - 1 ? TT - 1 : P);
  int xx, yy, zz;
  xcd_swz(8, 32, xx, yy, zz);
  const int b  = zz;
  const int t0 = yy * 128;
  const int n0 = xx * 128;
  if (mode == 1) { if (t0 + 128 <= P) return; }
  else           { if (t0 >= P) return; }
  const int row0 = b * TT + t0;
  __shared__ __align__(16) unsigned short Ah[128 * 40], Al[128 * 40];
  __shared__ __align__(16) unsigned short Bh[128 * 40], Bl[128 * 40];
  __shared__ float mus[128], rss[128];
  const int tid = threadIdx.x;
  if (tid < 128) {
    mus[tid] = stats[2 * (size_t)(row0 + tid)];
    rss[tid] = stats[2 * (size_t)(row0 + tid) + 1];
  }
  const int lane = tid & 63;
  const int wm = ((tid >> 6) >> 1) * 64, wn = ((tid >> 6) & 1) * 64;
  const int lm = lane & 15, lq = lane >> 4;
  f4v acc[4][4];
#pragma unroll
  for (int i = 0; i < 4; i++)
#pragma unroll
    for (int j = 0; j < 4; j++) acc[i][j] = (f4v){0.f, 0.f, 0.f, 0.f};

  for (int kt = 0; kt < D_MODEL; kt += 32) {
    __syncthreads();
#pragma unroll
    for (int q = 0; q < 2; q++) {
      int c = tid * 2 + q;
      int m = c >> 2, k8 = (c & 3) << 3;
      const float* src = &X[(size_t)(row0 + m) * D_MODEL + kt + k8];
      float mu = mus[m], rs = rss[m];
      u16x8 hv, lv;
#pragma unroll
      for (int i = 0; i < 8; i++) {
        float nv = (src[i] - mu) * rs * lng[kt + k8 + i] + lnb[kt + k8 + i];
        unsigned short h, l;
        split_bf16(nv, h, l);
        hv[i] = h; lv[i] = l;
      }
      *(u16x8*)&Ah[m * 40 + k8] = hv;
      *(u16x8*)&Al[m * 40 + k8] = lv;
      *(u16x8*)&Bh[m * 40 + k8] = *(const u16x8*)&WThi[(size_t)(n0 + m) * 1024 + kt + k8];
      *(u16x8*)&Bl[m * 40 + k8] = *(const u16x8*)&WTlo[(size_t)(n0 + m) * 1024 + kt + k8];
    }
    __syncthreads();
    s8v ah[4], al[4], bh[4], bl[4];
#pragma unroll
    for (int i = 0; i < 4; i++) {
      int ar = (wm + i * 16 + lm) * 40 + lq * 8;
      int br = (wn + i * 16 + lm) * 40 + lq * 8;
      ah[i] = *(const s8v*)&Ah[ar];
      al[i] = *(const s8v*)&Al[ar];
      bh[i] = *(const s8v*)&Bh[br];
      bl[i] = *(const s8v*)&Bl[br];
    }
#pragma unroll
    for (int mi = 0; mi < 4; mi++)
#pragma unroll
      for (int ni = 0; ni < 4; ni++) {
        acc[mi][ni] = __builtin_amdgcn_mfma_f32_16x16x32_bf16(ah[mi], bh[ni], acc[mi][ni], 0, 0, 0);
        acc[mi][ni] = __builtin_amdgcn_mfma_f32_16x16x32_bf16(ah[mi], bl[ni], acc[mi][ni], 0, 0, 0);
        acc[mi][ni] = __builtin_amdgcn_mfma_f32_16x16x32_bf16(al[mi], bh[ni], acc[mi][ni], 0, 0, 0);
      }
  }
#pragma unroll
  for (int mi = 0; mi < 4; mi++) {
#pragma unroll
    for (int r = 0; r < 4; r++) {
      int t = t0 + wm + mi * 16 + lq * 4 + r;
      bool ok = (mode == 1) ? (t >= P) : (t < P);
      if (!ok) continue;
      size_t orow = (mode == 2) ? ((size_t)b * P + t) : ((size_t)b * TT + t);
#pragma unroll
      for (int ni = 0; ni < 4; ni++)
        Y[orow * Nw + n0 + wn + ni * 16 + lm] = acc[mi][ni][r];
    }
  }
}

// ------- merged K/Q projection: one launch, all t-blocks active -------
__global__ __launch_bounds__(256) void gemm_kq_k(
    const float* __restrict__ X, const float* __restrict__ stats,
    const float* __restrict__ lng, const float* __restrict__ lnb,
    const unsigned short* __restrict__ KH, const unsigned short* __restrict__ KL,
    const unsigned short* __restrict__ QH, const unsigned short* __restrict__ QL,
    const int* __restrict__ pref, float* __restrict__ Y) {
  int P = pref[0]; P = P < 1 ? 1 : (P > TT - 1 ? TT - 1 : P);
  int xx, yy, zz;
  xcd_swz(4, 32, xx, yy, zz);
  const int b  = zz;
  const int t0 = yy * 128;
  const int n0 = xx * 128;
  const int row0 = b * TT + t0;
  const bool hasK = (t0 < P);
  const bool hasQ = (t0 + 128 > P);
  __shared__ __align__(16) unsigned short Ah[128 * 40], Al[128 * 40];
  __shared__ __align__(16) unsigned short Bh[128 * 40], Bl[128 * 40];
  __shared__ float mus[128], rss[128];
  const int tid = threadIdx.x;
  if (tid < 128) {
    mus[tid] = stats[2 * (size_t)(row0 + tid)];
    rss[tid] = stats[2 * (size_t)(row0 + tid) + 1];
  }
  const int lane = tid & 63;
  const int wm = ((tid >> 6) >> 1) * 64, wn = ((tid >> 6) & 1) * 64;
  const int lm = lane & 15, lq = lane >> 4;

  for (int pass = 0; pass < 2; pass++) {
    if (pass == 0 && !hasK) continue;
    if (pass == 1 && !hasQ) continue;
    const unsigned short* WThi = pass ? QH : KH;
    const unsigned short* WTlo = pass ? QL : KL;
    f4v acc[4][4];
#pragma unroll
    for (int i = 0; i < 4; i++)
#pragma unroll
      for (int j = 0; j < 4; j++) acc[i][j] = (f4v){0.f, 0.f, 0.f, 0.f};

    for (int kt = 0; kt < D_MODEL; kt += 32) {
      __syncthreads();
#pragma unroll
      for (int q = 0; q < 2; q++) {
        int c = tid * 2 + q;
        int m = c >> 2, k8 = (c & 3) << 3;
        const float* src = &X[(size_t)(row0 + m) * D_MODEL + kt + k8];
        float mu = mus[m], rs = rss[m];
        u16x8 hv, lv;
#pragma unroll
        for (int i = 0; i < 8; i++) {
          float nv = (src[i] - mu) * rs * lng[kt + k8 + i] + lnb[kt + k8 + i];
          unsigned short h, l;
          split_bf16(nv, h, l);
          hv[i] = h; lv[i] = l;
        }
        *(u16x8*)&Ah[m * 40 + k8] = hv;
        *(u16x8*)&Al[m * 40 + k8] = lv;
        *(u16x8*)&Bh[m * 40 + k8] = *(const u16x8*)&WThi[(size_t)(n0 + m) * 1024 + kt + k8];
        *(u16x8*)&Bl[m * 40 + k8] = *(const u16x8*)&WTlo[(size_t)(n0 + m) * 1024 + kt + k8];
      }
      __syncthreads();
      s8v ah[4], al[4], bh[4], bl[4];
#pragma unroll
      for (int i = 0; i < 4; i++) {
        int ar = (wm + i * 16 + lm) * 40 + lq * 8;
        int br = (wn + i * 16 + lm) * 40 + lq * 8;
        ah[i] = *(const s8v*)&Ah[ar];
        al[i] = *(const s8v*)&Al[ar];
        bh[i] = *(const s8v*)&Bh[br];
        bl[i] = *(const s8v*)&Bl[br];
      }
#pragma unroll
      for (int mi = 0; mi < 4; mi++)
#pragma unroll
        for (int ni = 0; ni < 4; ni++) {
          acc[mi][ni] = __builtin_amdgcn_mfma_f32_16x16x32_bf16(ah[mi], bh[ni], acc[mi][ni], 0, 0, 0);
          acc[mi][ni] = __builtin_amdgcn_mfma_f32_16x16x32_bf16(ah[mi], bl[ni], acc[mi][ni], 0, 0, 0);
          acc[mi][ni] = __builtin_amdgcn_mfma_f32_16x16x32_bf16(al[mi], bh[ni], acc[mi][ni], 0, 0, 0);
        }
    }
#pragma unroll
    for (int mi = 0; mi < 4; mi++) {
#pragma unroll
      for (int r = 0; r < 4; r++) {
        int t = t0 + wm + mi * 16 + lq * 4 + r;
        bool ok = pass ? (t >= P) : (t < P);
        if (!ok) continue;
#pragma unroll
        for (int ni = 0; ni < 4; ni++)
          Y[((size_t)b * TT + t) * 512 + n0 + wn + ni * 16 + lm] = acc[mi][ni][r];
      }
    }
  }
}

// ------------- G, M, C_v Gram reductions via MFMA (partials, no atomics) -------------
// LDS: keys transposed rank-major (current + shifted-prev copies) and values
// dh-major, bf16 hi/lo split; pad 136 elems -> 272B row stride = 2-way bank alias (free).
// wave0: G (K^T K, A-frag == B-frag); wave1: M (K^T K_prev); waves2,3: Cv (V^T K).
__global__ __launch_bounds__(256) void build_gmc_mfma_k(
    const float* __restrict__ Y1, const float* __restrict__ Y2,
    const int* __restrict__ pref,
    float* __restrict__ Gp, float* __restrict__ Mp, float* __restrict__ Cp) {
  int P = pref[0]; P = P < 1 ? 1 : (P > TT - 1 ? TT - 1 : P);
  const int c  = blockIdx.x;
  const int bh = blockIdx.y;
  const int b = bh >> 4, h = bh & 15;
  const int chunk = (P + TCH - 1) / TCH;
  const int tb = c * chunk;
  const int te = min(tb + chunk, P);

  __shared__ __align__(16) unsigned short kCh[32 * 136], kCl[32 * 136];
  __shared__ __align__(16) unsigned short kPh[32 * 136], kPl[32 * 136];
  __shared__ __align__(16) unsigned short vTh[64 * 136], vTl[64 * 136];

  const int tid = threadIdx.x;
  const int wid = tid >> 6, lane = tid & 63;
  const int lm = lane & 15, lq = lane >> 4;

  f4v acc[4];
#pragma unroll
  for (int i = 0; i < 4; i++) acc[i] = (f4v){0.f, 0.f, 0.f, 0.f};

  for (int t0 = tb; t0 < te; t0 += 128) {
    const int len = (te - t0 < 128) ? (te - t0) : 128;
    __syncthreads();
    // stage keys: rows 0..128 map t = t0-1+row; kC[u=row-1] current, kP[u=row] prev
    for (int e = tid; e < 129 * 8; e += 256) {
      int row = e >> 3, j4 = (e & 7) << 2;
      int t = t0 - 1 + row;
      float4 kv = make_float4(0.f, 0.f, 0.f, 0.f);
      if (row <= len && t >= 0)
        kv = *(const float4*)&Y1[((size_t)b * TT + t) * 512 + h * 32 + j4];
      unsigned short hh[4], ll[4];
      split_bf16(kv.x, hh[0], ll[0]); split_bf16(kv.y, hh[1], ll[1]);
      split_bf16(kv.z, hh[2], ll[2]); split_bf16(kv.w, hh[3], ll[3]);
      if (row >= 1) {
#pragma unroll
        for (int q = 0; q < 4; q++) {
          kCh[(j4 + q) * 136 + row - 1] = hh[q];
          kCl[(j4 + q) * 136 + row - 1] = ll[q];
        }
      }
      if (row < 128) {
#pragma unroll
        for (int q = 0; q < 4; q++) {
          kPh[(j4 + q) * 136 + row] = hh[q];
          kPl[(j4 + q) * 136 + row] = ll[q];
        }
      }
    }
    // stage values: v_t[d] at u = row
    for (int e = tid; e < 128 * 16; e += 256) {
      int row = e >> 4, dj = (e & 15) << 2;
      int t = t0 + row;
      float4 vv = make_float4(0.f, 0.f, 0.f, 0.f);
      if (row < len)
        vv = *(const float4*)&Y2[((size_t)b * P + t) * 1024 + h * 64 + dj];
      unsigned short hh[4], ll[4];
      split_bf16(vv.x, hh[0], ll[0]); split_bf16(vv.y, hh[1], ll[1]);
      split_bf16(vv.z, hh[2], ll[2]); split_bf16(vv.w, hh[3], ll[3]);
#pragma unroll
      for (int q = 0; q < 4; q++) {
        vTh[(dj + q) * 136 + row] = hh[q];
        vTl[(dj + q) * 136 + row] = ll[q];
      }
    }
    __syncthreads();

#pragma unroll
    for (int kk = 0; kk < 128; kk += 32) {
      const int off = kk + lq * 8;
      if (wid == 0) {
        s8v h0 = *(const s8v*)&kCh[(0 + lm) * 136 + off];
        s8v h1 = *(const s8v*)&kCh[(16 + lm) * 136 + off];
        s8v l0 = *(const s8v*)&kCl[(0 + lm) * 136 + off];
        s8v l1 = *(const s8v*)&kCl[(16 + lm) * 136 + off];
        acc[0] = __builtin_amdgcn_mfma_f32_16x16x32_bf16(h0, h0, acc[0], 0, 0, 0);
        acc[0] = __builtin_amdgcn_mfma_f32_16x16x32_bf16(h0, l0, acc[0], 0, 0, 0);
        acc[0] = __builtin_amdgcn_mfma_f32_16x16x32_bf16(l0, h0, acc[0], 0, 0, 0);
        acc[1] = __builtin_amdgcn_mfma_f32_16x16x32_bf16(h0, h1, acc[1], 0, 0, 0);
        acc[1] = __builtin_amdgcn_mfma_f32_16x16x32_bf16(h0, l1, acc[1], 0, 0, 0);
        acc[1] = __builtin_amdgcn_mfma_f32_16x16x32_bf16(l0, h1, acc[1], 0, 0, 0);
        acc[2] = __builtin_amdgcn_mfma_f32_16x16x32_bf16(h1, h0, acc[2], 0, 0, 0);
        acc[2] = __builtin_amdgcn_mfma_f32_16x16x32_bf16(h1, l0, acc[2], 0, 0, 0);
        acc[2] = __builtin_amdgcn_mfma_f32_16x16x32_bf16(l1, h0, acc[2], 0, 0, 0);
        acc[3] = __builtin_amdgcn_mfma_f32_16x16x32_bf16(h1, h1, acc[3], 0, 0, 0);
        acc[3] = __builtin_amdgcn_mfma_f32_16x16x32_bf16(h1, l1, acc[3], 0, 0, 0);
        acc[3] = __builtin_amdgcn_mfma_f32_16x16x32_bf16(l1, h1, acc[3], 0, 0, 0);
      } else if (wid == 1) {
        s8v ah0 = *(const s8v*)&kCh[(0 + lm) * 136 + off];
        s8v ah1 = *(const s8v*)&kCh[(16 + lm) * 136 + off];
        s8v al0 = *(const s8v*)&kCl[(0 + lm) * 136 + off];
        s8v al1 = *(const s8v*)&kCl[(16 + lm) * 136 + off];
        s8v bh0 = *(const s8v*)&kPh[(0 + lm) * 136 + off];
        s8v bh1 = *(const s8v*)&kPh[(16 + lm) * 136 + off];
        s8v bl0 = *(const s8v*)&kPl[(0 + lm) * 136 + off];
        s8v bl1 = *(const s8v*)&kPl[(16 + lm) * 136 + off];
        acc[0] = __builtin_amdgcn_mfma_f32_16x16x32_bf16(ah0, bh0, acc[0], 0, 0, 0);
        acc[0] = __builtin_amdgcn_mfma_f32_16x16x32_bf16(ah0, bl0, acc[0], 0, 0, 0);
        acc[0] = __builtin_amdgcn_mfma_f32_16x16x32_bf16(al0, bh0, acc[0], 0, 0, 0);
        acc[1] = __builtin_amdgcn_mfma_f32_16x16x32_bf16(ah0, bh1, acc[1], 0, 0, 0);
        acc[1] = __builtin_amdgcn_mfma_f32_16x16x32_bf16(ah0, bl1, acc[1], 0, 0, 0);
        acc[1] = __builtin_amdgcn_mfma_f32_16x16x32_bf16(al0, bh1, acc[1], 0, 0, 0);
        acc[2] = __builtin_amdgcn_mfma_f32_16x16x32_bf16(ah1, bh0, acc[2], 0, 0, 0);
        acc[2] = __builtin_amdgcn_mfma_f32_16x16x32_bf16(ah1, bl0, acc[2], 0, 0, 0);
        acc[2] = __builtin_amdgcn_mfma_f32_16x16x32_bf16(al1, bh0, acc[2], 0, 0, 0);
        acc[3] = __builtin_amdgcn_mfma_f32_16x16x32_bf16(ah1, bh1, acc[3], 0, 0, 0);
        acc[3] = __builtin_amdgcn_mfma_f32_16x16x32_bf16(ah1, bl1, acc[3], 0, 0, 0);
        acc[3] = __builtin_amdgcn_mfma_f32_16x16x32_bf16(al1, bh1, acc[3], 0, 0, 0);
      } else {
        const int d0 = (wid - 2) * 32;
        s8v vh0 = *(const s8v*)&vTh[(d0 + lm) * 136 + off];
        s8v vh1 = *(const s8v*)&vTh[(d0 + 16 + lm) * 136 + off];
        s8v vl0 = *(const s8v*)&vTl[(d0 + lm) * 136 + off];
        s8v vl1 = *(const s8v*)&vTl[(d0 + 16 + lm) * 136 + off];
        s8v kh0 = *(const s8v*)&kCh[(0 + lm) * 136 + off];
        s8v kh1 = *(const s8v*)&kCh[(16 + lm) * 136 + off];
        s8v kl0 = *(const s8v*)&kCl[(0 + lm) * 136 + off];
        s8v kl1 = *(const s8v*)&kCl[(16 + lm) * 136 + off];
        acc[0] = __builtin_amdgcn_mfma_f32_16x16x32_bf16(vh0, kh0, acc[0], 0, 0, 0);
        acc[0] = __builtin_amdgcn_mfma_f32_16x16x32_bf16(vh0, kl0, acc[0], 0, 0, 0);
        acc[0] = __builtin_amdgcn_mfma_f32_16x16x32_bf16(vl0, kh0, acc[0], 0, 0, 0);
        acc[1] = __builtin_amdgcn_mfma_f32_16x16x32_bf16(vh0, kh1, acc[1], 0, 0, 0);
        acc[1] = __builtin_amdgcn_mfma_f32_16x16x32_bf16(vh0, kl1, acc[1], 0, 0, 0);
        acc[1] = __builtin_amdgcn_mfma_f32_16x16x32_bf16(vl0, kh1, acc[1], 0, 0, 0);
        acc[2] = __builtin_amdgcn_mfma_f32_16x16x32_bf16(vh1, kh0, acc[2], 0, 0, 0);
        acc[2] = __builtin_amdgcn_mfma_f32_16x16x32_bf16(vh1, kl0, acc[2], 0, 0, 0);
        acc[2] = __builtin_amdgcn_mfma_f32_16x16x32_bf16(vl1, kh0, acc[2], 0, 0, 0);
        acc[3] = __builtin_amdgcn_mfma_f32_16x16x32_bf16(vh1, kh1, acc[3], 0, 0, 0);
        acc[3] = __builtin_amdgcn_mfma_f32_16x16x32_bf16(vh1, kl1, acc[3], 0, 0, 0);
        acc[3] = __builtin_amdgcn_mfma_f32_16x16x32_bf16(vl1, kh1, acc[3], 0, 0, 0);
      }
    }
  }

  // write partials (D layout: col = lm, row = lq*4 + r)
  if (wid < 2) {
    float* dst = (wid == 0 ? Gp : Mp) + (size_t)(c * 64 + bh) * 1024;
#pragma unroll
    for (int t = 0; t < 4; t++) {
      int i0 = (t >> 1) * 16, j0 = (t & 1) * 16;
#pragma unroll
      for (int r = 0; r < 4; r++)
        dst[(i0 + lq * 4 + r) * 32 + j0 + lm] = acc[t][r];
    }
  } else {
    float* dst = Cp + (size_t)(c * 64 + bh) * 2048;
#pragma unroll
    for (int t = 0; t < 4; t++) {
      int d0 = (wid - 2) * 32 + (t >> 1) * 16, j0 = (t & 1) * 16;
#pragma unroll
      for (int r = 0; r < 4; r++)
        dst[(d0 + lq * 4 + r) * 32 + j0 + lm] = acc[t][r];
    }
  }
}

// ------- per-(b,h) operator: chol, G^{-1}, A_w, sigma, F = Cv*Gi*(s*M*Gi)^4 -------
__global__ __launch_bounds__(256) void solve_op_k(
    const float* __restrict__ Gp, const float* __restrict__ Mp,
    const float* __restrict__ Cp, const float* __restrict__ lridge,
    const float* __restrict__ lgamma, float* __restrict__ Ft) {
  __shared__ float Gs[32 * 33];
  __shared__ float Ms[32 * 32];
  __shared__ float Gi[32 * 32];
  __shared__ float W1[32 * 33];
  __shared__ float Aw[32 * 33];
  __shared__ float Nn[32 * 32];
  __shared__ float N2[32 * 32];
  __shared__ float T1[32 * 32];
  __shared__ float Cs[64 * 32];
  __shared__ float red[256];
  __shared__ float vv[32], uu[32];
  const int bh = blockIdx.x;
  const int tid = threadIdx.x;
  const float ridge = expf(lridge[0]);

  for (int e = tid; e < 1024; e += 256) {
    int i = e >> 5, j = e & 31;
    float g = 0.f, m = 0.f;
#pragma unroll
    for (int cc = 0; cc < TCH; cc++) {
      g += Gp[(size_t)(cc * 64 + bh) * 1024 + e];
      m += Mp[(size_t)(cc * 64 + bh) * 1024 + e];
    }
    if (i == j) g += ridge;
    Gs[i * 33 + j] = g;
    Ms[e] = m;
  }
  for (int e = tid; e < 2048; e += 256) {
    float s = 0.f;
#pragma unroll
    for (int cc = 0; cc < TCH; cc++) s += Cp[(size_t)(cc * 64 + bh) * 2048 + e];
    Cs[e] = s;
  }
  __syncthreads();

  for (int j = 0; j < 32; j++) {
    float d = Gs[j * 33 + j];
    __syncthreads();
    float inv = 1.0f / sqrtf(d);
    if (tid >= j && tid < 32) Gs[tid * 33 + j] *= inv;
    __syncthreads();
    int w = 31 - j;
    for (int e = tid; e < w * w; e += 256) {
      int i = j + 1 + e / w, k = j + 1 + e % w;
      Gs[i * 33 + k] -= Gs[i * 33 + j] * Gs[k * 33 + j];
    }
    __syncthreads();
  }

  if (tid < 32) {
    const int c = tid;
    for (int i = 0; i < 32; i++) W1[i * 33 + c] = (i == c) ? 1.0f : 0.0f;
    for (int i = 0; i < 32; i++) {
      float s = W1[i * 33 + c];
      for (int j = 0; j < i; j++) s -= Gs[i * 33 + j] * W1[j * 33 + c];
      W1[i * 33 + c] = s / Gs[i * 33 + i];
    }
    for (int i = 31; i >= 0; i--) {
      float s = W1[i * 33 + c];
      for (int j = i + 1; j < 32; j++) s -= Gs[j * 33 + i] * W1[j * 33 + c];
      W1[i * 33 + c] = s / Gs[i * 33 + i];
    }
    for (int i = 0; i < 32; i++) Gi[i * 32 + c] = W1[i * 33 + c];
  }
  __syncthreads();
  if (tid < 32) {
    const int c = tid;
    for (int i = 0; i < 32; i++) {
      float s = Ms[i * 32 + c];
      for (int j = 0; j < i; j++) s -= Gs[i * 33 + j] * W1[j * 33 + c];
      W1[i * 33 + c] = s / Gs[i * 33 + i];
    }
  }
  __syncthreads();
  if (tid < 32) {
    const int c = tid;
    for (int i = 0; i < 32; i++) {
      float s = W1[c * 33 + i];
      for (int j = 0; j < i; j++) s -= Gs[i * 33 + j] * Aw[j * 33 + c];
      Aw[i * 33 + c] = s / Gs[i * 33 + i];
    }
  }
  __syncthreads();

  float s0 = 0.0f;
  for (int e = tid; e < 1024; e += 256) {
    float a = Aw[(e >> 5) * 33 + (e & 31)];
    s0 += a * a;
  }
  red[tid] = s0;
  __syncthreads();
  for (int off = 128; off > 0; off >>= 1) {
    if (tid < off) red[tid] += red[tid + off];
    __syncthreads();
  }
  float frob2 = red[0];
  float sigma;
  if (frob2 <= 1.0f) {
    sigma = sqrtf(frob2);
  } else {
    if (tid < 32) vv[tid] = 1.0f + 0.001f * (float)tid;
    __syncthreads();
    for (int it = 0; it < 64; it++) {
      if (tid < 32) {
        float s = 0;
        for (int j = 0; j < 32; j++) s += Aw[tid * 33 + j] * vv[j];
        uu[tid] = s;
      }
      __syncthreads();
      if (tid == 0) {
        float n = 0;
        for (int j = 0; j < 32; j++) n += uu[j] * uu[j];
        red[0] = sqrtf(n);
      }
      __syncthreads();
      float nu = fmaxf(red[0], 1e-30f);
      if (tid < 32) uu[tid] /= nu;
      __syncthreads();
      if (tid < 32) {
        float s = 0;
        for (int j = 0; j < 32; j++) s += Aw[j * 33 + tid] * uu[j];
        vv[tid] = s;
      }
      __syncthreads();
      if (tid == 0) {
        float n = 0;
        for (int j = 0; j < 32; j++) n += vv[j] * vv[j];
        red[0] = sqrtf(n);
      }
      __syncthreads();
      float nv = fmaxf(red[0], 1e-30f);
      if (tid < 32) vv[tid] /= nv;
      __syncthreads();
    }
    sigma = red[0];
  }
  float gamma_c = fminf(expf(lgamma[0]), 1.0f);
  float scale = gamma_c / fmaxf(fmaxf(sigma, 1e-8f), 1.0f);

  for (int e = tid; e < 1024; e += 256) {
    int i = e >> 5, c = e & 31;
    float s = 0;
#pragma unroll
    for (int k = 0; k < 32; k++) s += Ms[i * 32 + k] * Gi[k * 32 + c];
    Nn[e] = scale * s;
  }
  __syncthreads();
  for (int e = tid; e < 1024; e += 256) {
    int i = e >> 5, c = e & 31;
    float s = 0;
#pragma unroll
    for (int k = 0; k < 32; k++) s += Nn[i * 32 + k] * Nn[k * 32 + c];
    N2[e] = s;
  }
  __syncthreads();
  for (int e = tid; e < 1024; e += 256) {
    int i = e >> 5, c = e & 31;
    float s = 0;
#pragma unroll
    for (int k = 0; k < 32; k++) s += N2[i * 32 + k] * N2[k * 32 + c];
    Ms[e] = s;
  }
  __syncthreads();
  for (int e = tid; e < 1024; e += 256) {
    int i = e >> 5, c = e & 31;
    float s = 0;
#pragma unroll
    for (int k = 0; k < 32; k++) s += Gi[i * 32 + k] * Ms[k * 32 + c];
    T1[e] = s;
  }
  __syncthreads();
  for (int e = tid; e < 2048; e += 256) {
    int j = e >> 6, d = e & 63;
    float s = 0;
#pragma unroll
    for (int k = 0; k < 32; k++) s += Cs[d * 32 + k] * T1[k * 32 + j];
    Ft[(size_t)bh * 2048 + e] = s;
  }
}

// ------------- apply F^T per (head, 128-token chunk) -> full_hi (bf16) -------------
__global__ __launch_bounds__(256) void apply_k(const float* __restrict__ Y1,
                                               const float* __restrict__ Ft,
                                               unsigned short* __restrict__ FH) {
  __shared__ float xs[128 * 32];
  const int h = blockIdx.y;
  const int r0 = blockIdx.x * 128;
  const int bh = (r0 >> 12) * NH + h;
  const int tid = threadIdx.x;
  const int d = tid & 63, t0 = tid >> 6;
  float fcol[32];
  const float* fb = &Ft[(size_t)bh * 2048 + d];
#pragma unroll
  for (int j = 0; j < 32; j++) fcol[j] = fb[j * 64];
  for (int e = tid; e < 1024; e += 256) {
    int row = e >> 3, j4 = (e & 7) << 2;
    *(float4*)&xs[row * 32 + j4] =
        *(const float4*)&Y1[((size_t)(r0 + row)) * 512 + h * 32 + j4];
  }
  __syncthreads();
  for (int tl = t0; tl < 128; tl += 4) {
    float s = 0;
#pragma unroll
    for (int j = 0; j < 32; j++) s += xs[tl * 32 + j] * fcol[j];
    FH[((size_t)(r0 + tl)) * 1024 + h * 64 + d] = bf16_rne(s);
  }
}

// ------------- output GEMM (MFMA): out = sg * full @ Wo ; A=hi, B=hi+lo -------------
__global__ __launch_bounds__(256) void gemm_out_k(
    const unsigned short* __restrict__ FH,
    const unsigned short* __restrict__ WThi, const unsigned short* __restrict__ WTlo,
    const float* __restrict__ alpha, float* __restrict__ out) {
  int xx, yy, zz;
  xcd_swz(8, 128, xx, yy, zz);
  const int m0 = yy * 128;
  const int n0 = xx * 128;
  __shared__ __align__(16) unsigned short Ah[128 * 40];
  __shared__ __align__(16) unsigned short Bh[128 * 40], Bl[128 * 40];
  const int tid = threadIdx.x;
  const int lane = tid & 63;
  const int wm = ((tid >> 6) >> 1) * 64, wn = ((tid >> 6) & 1) * 64;
  const int lm = lane & 15, lq = lane >> 4;
  f4v acc[4][4];
#pragma unroll
  for (int i = 0; i < 4; i++)
#pragma unroll
    for (int j = 0; j < 4; j++) acc[i][j] = (f4v){0.f, 0.f, 0.f, 0.f};

  for (int kt = 0; kt < D_MODEL; kt += 32) {
    __syncthreads();
#pragma unroll
    for (int q = 0; q < 2; q++) {
      int c = tid * 2 + q;
      int m = c >> 2, k8 = (c & 3) << 3;
      *(u16x8*)&Ah[m * 40 + k8] = *(const u16x8*)&FH[(size_t)(m0 + m) * 1024 + kt + k8];
      *(u16x8*)&Bh[m * 40 + k8] = *(const u16x8*)&WThi[(size_t)(n0 + m) * 1024 + kt + k8];
      *(u16x8*)&Bl[m * 40 + k8] = *(const u16x8*)&WTlo[(size_t)(n0 + m) * 1024 + kt + k8];
    }
    __syncthreads();
    s8v ah[4], bh[4], bl[4];
#pragma unroll
    for (int i = 0; i < 4; i++) {
      ah[i] = *(const s8v*)&Ah[(wm + i * 16 + lm) * 40 + lq * 8];
      bh[i] = *(const s8v*)&Bh[(wn + i * 16 + lm) * 40 + lq * 8];
      bl[i] = *(const s8v*)&Bl[(wn + i * 16 + lm) * 40 + lq * 8];
    }
#pragma unroll
    for (int mi = 0; mi < 4; mi++)
#pragma unroll
      for (int ni = 0; ni < 4; ni++) {
        acc[mi][ni] = __builtin_amdgcn_mfma_f32_16x16x32_bf16(ah[mi], bh[ni], acc[mi][ni], 0, 0, 0);
        acc[mi][ni] = __builtin_amdgcn_mfma_f32_16x16x32_bf16(ah[mi], bl[ni], acc[mi][ni], 0, 0, 0);
      }
  }
  float sg = 1.0f / (1.0f + expf(-alpha[0]));
#pragma unroll
  for (int mi = 0; mi < 4; mi++)
#pragma unroll
    for (int r = 0; r < 4; r++) {
      size_t orow = (size_t)(m0 + wm + mi * 16 + lq * 4 + r);
#pragma unroll
      for (int ni = 0; ni < 4; ni++)
        out[orow * 1024 + n0 + wn + ni * 16 + lm] = sg * acc[mi][ni][r];
    }
}

extern "C" void kernel_launch(void* const* d_in, const int* in_sizes, int n_in,
                              void* d_out, int out_size, void* d_ws, size_t ws_size,
                              hipStream_t stream) {
  const float* X      = (const float*)d_in[0];
  const float* Wk     = (const float*)d_in[1];
  const float* Wq     = (const float*)d_in[2];
  const float* Wv     = (const float*)d_in[3];
  const float* Wo     = (const float*)d_in[4];
  const float* lng    = (const float*)d_in[5];
  const float* lnb    = (const float*)d_in[6];
  const float* alpha  = (const float*)d_in[7];
  const float* lridge = (const float*)d_in[8];
  const float* lgamma = (const float*)d_in[9];
  const int*   pref   = (const int*)d_in[10];
  float* out = (float*)d_out;
  char* ws = (char*)d_ws;
  float* stats = (float*)(ws + OFF_STATS);
  float* Gp    = (float*)(ws + OFF_GP);
  float* Mp    = (float*)(ws + OFF_MP);
  float* Cp    = (float*)(ws + OFF_CP);
  float* Ft    = (float*)(ws + OFF_FT);
  unsigned short* WKH = (unsigned short*)(ws + OFF_WKH);
  unsigned short* WKL = (unsigned short*)(ws + OFF_WKL);
  unsigned short* WQH = (unsigned short*)(ws + OFF_WQH);
  unsigned short* WQL = (unsigned short*)(ws + OFF_WQL);
  unsigned short* WVH = (unsigned short*)(ws + OFF_WVH);
  unsigned short* WVL = (unsigned short*)(ws + OFF_WVL);
  unsigned short* WOH = (unsigned short*)(ws + OFF_WOH);
  unsigned short* WOL = (unsigned short*)(ws + OFF_WOL);
  float* Y1 = (float*)(ws + OFF_Y1);
  float* Y2 = (float*)(ws + OFF_Y2);
  unsigned short* FH = (unsigned short*)(ws + OFF_FH);

  ln_stats_k<<<16384, 256, 0, stream>>>(X, stats);
  prep_w_k<<<dim3(16, 32), 256, 0, stream>>>(Wk, 512, WKH, WKL);
  prep_w_k<<<dim3(16, 32), 256, 0, stream>>>(Wq, 512, WQH, WQL);
  prep_w_k<<<dim3(32, 32), 256, 0, stream>>>(Wv, 1024, WVH, WVL);
  prep_w_k<<<dim3(32, 32), 256, 0, stream>>>(Wo, 1024, WOH, WOL);
  gemm_kq_k<<<dim3(4, 32, NB), 256, 0, stream>>>(X, stats, lng, lnb, WKH, WKL, WQH, WQL, pref, Y1);
  gemm_proj_k<<<dim3(8, 32, NB), 256, 0, stream>>>(X, stats, lng, lnb, WVH, WVL, 1024, pref, 2, Y2);
  build_gmc_mfma_k<<<dim3(TCH, 64), 256, 0, stream>>>(Y1, Y2, pref, Gp, Mp, Cp);
  solve_op_k<<<64, 256, 0, stream>>>(Gp, Mp, Cp, lridge, lgamma, Ft);
  apply_k<<<dim3(128, NH), 256, 0, stream>>>(Y1, Ft, FH);
  gemm_out_k<<<dim3(8, 128), 256, 0, stream>>>(FH, WOH, WOL, alpha, out);
}

// Round 3
// 467.406 us; speedup vs baseline: 1.4089x; 1.0540x over previous
//
#include <hip/hip_runtime.h>
#include <math.h>

#define D_MODEL 1024
#define TT 4096
#define NB 4
#define NH 16
#define TCH 8

typedef __attribute__((ext_vector_type(8))) short s8v;
typedef __attribute__((ext_vector_type(4))) float f4v;
typedef __attribute__((ext_vector_type(8))) unsigned short u16x8;

// ---- workspace layout (bytes); peak ~88 MB (proven budget 100 MB) ----
#define OFF_STATS ((size_t)0)
#define OFF_GP    ((size_t)(1) << 20)    // 8*64*1024*4 = 2 MB partials
#define OFF_MP    ((size_t)(3) << 20)    // 2 MB
#define OFF_CP    ((size_t)(5) << 20)    // 8*64*2048*4 = 4 MB
#define OFF_FT    ((size_t)(9) << 20)    // 512 KB
#define OFF_WKH   ((size_t)(10) << 20)
#define OFF_WKL   ((size_t)(11) << 20)
#define OFF_WQH   ((size_t)(12) << 20)
#define OFF_WQL   ((size_t)(13) << 20)
#define OFF_WVH   ((size_t)(14) << 20)
#define OFF_WVL   ((size_t)(16) << 20)
#define OFF_WOH   ((size_t)(18) << 20)
#define OFF_WOL   ((size_t)(20) << 20)
#define OFF_Y1    ((size_t)(22) << 20)   // 32 MB
#define OFF_Y2    ((size_t)(54) << 20)   // P*NB*1024*4; FH overlays after build_gmc
#define OFF_FH    OFF_Y2

__device__ __forceinline__ unsigned short bf16_rne(float x) {
  unsigned u = __float_as_uint(x);
  return (unsigned short)((u + 0x7fffu + ((u >> 16) & 1u)) >> 16);
}
__device__ __forceinline__ void split_bf16(float x, unsigned short& h, unsigned short& l) {
  unsigned u = __float_as_uint(x);
  unsigned r = (u + 0x7fffu + ((u >> 16) & 1u)) & 0xffff0000u;
  h = (unsigned short)(r >> 16);
  float res = x - __uint_as_float(r);
  l = bf16_rne(res);
}

// async global->LDS, 16 B per lane; lds base must be wave-uniform (HW adds lane*16)
__device__ __forceinline__ void gll16(unsigned short* lds, const unsigned short* g) {
  __builtin_amdgcn_global_load_lds(
      (__attribute__((address_space(1))) void*)(void*)(g),
      (__attribute__((address_space(3))) void*)(lds), 16, 0, 0);
}

// bijective XCD swizzle: the gx blocks sharing one (y,z) land consecutively on ONE
// XCD; (y,z) values strided by 8 across XCDs (keeps P-masked kernels balanced).
__device__ __forceinline__ void xcd_swz(int gx, int gy, int& x, int& y, int& z) {
  int wg = blockIdx.x + gx * (blockIdx.y + gy * blockIdx.z);
  int k = wg & 7, j = wg >> 3;
  x = j % gx;
  int yz = k + ((j / gx) << 3);
  y = yz % gy;
  z = yz / gy;
}

// ---------------- LayerNorm statistics: one block per row ----------------
__global__ __launch_bounds__(256) void ln_stats_k(const float* __restrict__ X,
                                                  float* __restrict__ stats) {
  int r = blockIdx.x;
  const float4 v = ((const float4*)(X + (size_t)r * D_MODEL))[threadIdx.x];
  float s  = v.x + v.y + v.z + v.w;
  float ss = v.x * v.x + v.y * v.y + v.z * v.z + v.w * v.w;
#pragma unroll
  for (int off = 32; off > 0; off >>= 1) {
    s  += __shfl_down(s, off, 64);
    ss += __shfl_down(ss, off, 64);
  }
  __shared__ float as_[4], bs_[4];
  int w = threadIdx.x >> 6, lane = threadIdx.x & 63;
  if (lane == 0) { as_[w] = s; bs_[w] = ss; }
  __syncthreads();
  if (threadIdx.x == 0) {
    float S  = as_[0] + as_[1] + as_[2] + as_[3];
    float SS = bs_[0] + bs_[1] + bs_[2] + bs_[3];
    float mu  = S * (1.0f / D_MODEL);
    float var = SS * (1.0f / D_MODEL) - mu * mu;
    stats[2 * (size_t)r]     = mu;
    stats[2 * (size_t)r + 1] = 1.0f / sqrtf(var + 1e-5f);
  }
}

// ------- prep: transpose W[K][N] -> WT_hi/lo [N][K] bf16 split -------
__global__ __launch_bounds__(256) void prep_w_k(const float* __restrict__ W, int N,
                                                unsigned short* __restrict__ Thi,
                                                unsigned short* __restrict__ Tlo) {
  __shared__ float tileT[32 * 33];
  const int n0 = blockIdx.x * 32, k0 = blockIdx.y * 32;
  const int tid = threadIdx.x;
  {
    int k_l = tid >> 3, n4 = (tid & 7) << 2;
    float4 v = *(const float4*)&W[(size_t)(k0 + k_l) * N + n0 + n4];
    tileT[(n4 + 0) * 33 + k_l] = v.x;
    tileT[(n4 + 1) * 33 + k_l] = v.y;
    tileT[(n4 + 2) * 33 + k_l] = v.z;
    tileT[(n4 + 3) * 33 + k_l] = v.w;
  }
  __syncthreads();
  {
    int n_l = tid >> 3, k4 = (tid & 7) << 2;
    unsigned short h[4], l[4];
#pragma unroll
    for (int i = 0; i < 4; i++) split_bf16(tileT[n_l * 33 + k4 + i], h[i], l[i]);
    *(ushort4*)&Thi[(size_t)(n0 + n_l) * 1024 + k0 + k4] = make_ushort4(h[0], h[1], h[2], h[3]);
    *(ushort4*)&Tlo[(size_t)(n0 + n_l) * 1024 + k0 + k4] = make_ushort4(l[0], l[1], l[2], l[3]);
  }
}

// ------- fused LN + projection GEMM, split-bf16 MFMA (3 products) -------
// A reg-staged (LN fusion); B via global_load_lds width-16, linear [128][32] LDS.
// mode 2: rows t<P, Wv -> Y2 compact
__global__ __launch_bounds__(256) void gemm_proj_k(
    const float* __restrict__ X, const float* __restrict__ stats,
    const float* __restrict__ lng, const float* __restrict__ lnb,
    const unsigned short* __restrict__ WThi, const unsigned short* __restrict__ WTlo,
    int Nw, const int* __restrict__ pref, int mode, float* __restrict__ Y) {
  int P = pref[0]; P = P < 1 ? 1 : (P > TT - 1 ? TT - 1 : P);
  int xx, yy, zz;
  xcd_swz(8, 32, xx, yy, zz);
  const int b  = zz;
  const int t0 = yy * 128;
  const int n0 = xx * 128;
  if (mode == 1) { if (t0 + 128 <= P) return; }
  else           { if (t0 >= P) return; }
  const int row0 = b * TT + t0;
  __shared__ __align__(16) unsigned short Ah[128 * 40], Al[128 * 40];
  __shared__ __align__(16) unsigned short Bh[128 * 32], Bl[128 * 32];
  __shared__ float mus[128], rss[128];
  const int tid = threadIdx.x;
  if (tid < 128) {
    mus[tid] = stats[2 * (size_t)(row0 + tid)];
    rss[tid] = stats[2 * (size_t)(row0 + tid) + 1];
  }
  const int lane = tid & 63;
  const int wid  = tid >> 6;
  const int wm = (wid >> 1) * 64, wn = (wid & 1) * 64;
  const int lm = lane & 15, lq = lane >> 4;
  const int srow = lane >> 2, scol = (lane & 3) << 3;  // staging: 16 rows x 4 chunks
  f4v acc[4][4];
#pragma unroll
  for (int i = 0; i < 4; i++)
#pragma unroll
    for (int j = 0; j < 4; j++) acc[i][j] = (f4v){0.f, 0.f, 0.f, 0.f};

  for (int kt = 0; kt < D_MODEL; kt += 32) {
    __syncthreads();
#pragma unroll
    for (int s = 0; s < 2; s++) {
      int seg = wid * 2 + s;
      int brow = n0 + seg * 16 + srow;
      gll16(&Bh[seg * 512], &WThi[(size_t)brow * 1024 + kt + scol]);
      gll16(&Bl[seg * 512], &WTlo[(size_t)brow * 1024 + kt + scol]);
    }
#pragma unroll
    for (int q = 0; q < 2; q++) {
      int c = tid * 2 + q;
      int m = c >> 2, k8 = (c & 3) << 3;
      const float* src = &X[(size_t)(row0 + m) * D_MODEL + kt + k8];
      float mu = mus[m], rs = rss[m];
      u16x8 hv, lv;
#pragma unroll
      for (int i = 0; i < 8; i++) {
        float nv = (src[i] - mu) * rs * lng[kt + k8 + i] + lnb[kt + k8 + i];
        unsigned short h, l;
        split_bf16(nv, h, l);
        hv[i] = h; lv[i] = l;
      }
      *(u16x8*)&Ah[m * 40 + k8] = hv;
      *(u16x8*)&Al[m * 40 + k8] = lv;
    }
    __syncthreads();
    s8v ah[4], al[4], bh[4], bl[4];
#pragma unroll
    for (int i = 0; i < 4; i++) {
      int ar = (wm + i * 16 + lm) * 40 + lq * 8;
      int br = (wn + i * 16 + lm) * 32 + lq * 8;
      ah[i] = *(const s8v*)&Ah[ar];
      al[i] = *(const s8v*)&Al[ar];
      bh[i] = *(const s8v*)&Bh[br];
      bl[i] = *(const s8v*)&Bl[br];
    }
#pragma unroll
    for (int mi = 0; mi < 4; mi++)
#pragma unroll
      for (int ni = 0; ni < 4; ni++) {
        acc[mi][ni] = __builtin_amdgcn_mfma_f32_16x16x32_bf16(ah[mi], bh[ni], acc[mi][ni], 0, 0, 0);
        acc[mi][ni] = __builtin_amdgcn_mfma_f32_16x16x32_bf16(ah[mi], bl[ni], acc[mi][ni], 0, 0, 0);
        acc[mi][ni] = __builtin_amdgcn_mfma_f32_16x16x32_bf16(al[mi], bh[ni], acc[mi][ni], 0, 0, 0);
      }
  }
#pragma unroll
  for (int mi = 0; mi < 4; mi++) {
#pragma unroll
    for (int r = 0; r < 4; r++) {
      int t = t0 + wm + mi * 16 + lq * 4 + r;
      bool ok = (mode == 1) ? (t >= P) : (t < P);
      if (!ok) continue;
      size_t orow = (mode == 2) ? ((size_t)b * P + t) : ((size_t)b * TT + t);
#pragma unroll
      for (int ni = 0; ni < 4; ni++)
        Y[orow * Nw + n0 + wn + ni * 16 + lm] = acc[mi][ni][r];
    }
  }
}

// ------- merged K/Q projection: one launch, all t-blocks active -------
__global__ __launch_bounds__(256) void gemm_kq_k(
    const float* __restrict__ X, const float* __restrict__ stats,
    const float* __restrict__ lng, const float* __restrict__ lnb,
    const unsigned short* __restrict__ KH, const unsigned short* __restrict__ KL,
    const unsigned short* __restrict__ QH, const unsigned short* __restrict__ QL,
    const int* __restrict__ pref, float* __restrict__ Y) {
  int P = pref[0]; P = P < 1 ? 1 : (P > TT - 1 ? TT - 1 : P);
  int xx, yy, zz;
  xcd_swz(4, 32, xx, yy, zz);
  const int b  = zz;
  const int t0 = yy * 128;
  const int n0 = xx * 128;
  const int row0 = b * TT + t0;
  const bool hasK = (t0 < P);
  const bool hasQ = (t0 + 128 > P);
  __shared__ __align__(16) unsigned short Ah[128 * 40], Al[128 * 40];
  __shared__ __align__(16) unsigned short Bh[128 * 32], Bl[128 * 32];
  __shared__ float mus[128], rss[128];
  const int tid = threadIdx.x;
  if (tid < 128) {
    mus[tid] = stats[2 * (size_t)(row0 + tid)];
    rss[tid] = stats[2 * (size_t)(row0 + tid) + 1];
  }
  const int lane = tid & 63;
  const int wid  = tid >> 6;
  const int wm = (wid >> 1) * 64, wn = (wid & 1) * 64;
  const int lm = lane & 15, lq = lane >> 4;
  const int srow = lane >> 2, scol = (lane & 3) << 3;

  for (int pass = 0; pass < 2; pass++) {
    if (pass == 0 && !hasK) continue;
    if (pass == 1 && !hasQ) continue;
    const unsigned short* WThi = pass ? QH : KH;
    const unsigned short* WTlo = pass ? QL : KL;
    f4v acc[4][4];
#pragma unroll
    for (int i = 0; i < 4; i++)
#pragma unroll
      for (int j = 0; j < 4; j++) acc[i][j] = (f4v){0.f, 0.f, 0.f, 0.f};

    for (int kt = 0; kt < D_MODEL; kt += 32) {
      __syncthreads();
#pragma unroll
      for (int s = 0; s < 2; s++) {
        int seg = wid * 2 + s;
        int brow = n0 + seg * 16 + srow;
        gll16(&Bh[seg * 512], &WThi[(size_t)brow * 1024 + kt + scol]);
        gll16(&Bl[seg * 512], &WTlo[(size_t)brow * 1024 + kt + scol]);
      }
#pragma unroll
      for (int q = 0; q < 2; q++) {
        int c = tid * 2 + q;
        int m = c >> 2, k8 = (c & 3) << 3;
        const float* src = &X[(size_t)(row0 + m) * D_MODEL + kt + k8];
        float mu = mus[m], rs = rss[m];
        u16x8 hv, lv;
#pragma unroll
        for (int i = 0; i < 8; i++) {
          float nv = (src[i] - mu) * rs * lng[kt + k8 + i] + lnb[kt + k8 + i];
          unsigned short h, l;
          split_bf16(nv, h, l);
          hv[i] = h; lv[i] = l;
        }
        *(u16x8*)&Ah[m * 40 + k8] = hv;
        *(u16x8*)&Al[m * 40 + k8] = lv;
      }
      __syncthreads();
      s8v ah[4], al[4], bh[4], bl[4];
#pragma unroll
      for (int i = 0; i < 4; i++) {
        int ar = (wm + i * 16 + lm) * 40 + lq * 8;
        int br = (wn + i * 16 + lm) * 32 + lq * 8;
        ah[i] = *(const s8v*)&Ah[ar];
        al[i] = *(const s8v*)&Al[ar];
        bh[i] = *(const s8v*)&Bh[br];
        bl[i] = *(const s8v*)&Bl[br];
      }
#pragma unroll
      for (int mi = 0; mi < 4; mi++)
#pragma unroll
        for (int ni = 0; ni < 4; ni++) {
          acc[mi][ni] = __builtin_amdgcn_mfma_f32_16x16x32_bf16(ah[mi], bh[ni], acc[mi][ni], 0, 0, 0);
          acc[mi][ni] = __builtin_amdgcn_mfma_f32_16x16x32_bf16(ah[mi], bl[ni], acc[mi][ni], 0, 0, 0);
          acc[mi][ni] = __builtin_amdgcn_mfma_f32_16x16x32_bf16(al[mi], bh[ni], acc[mi][ni], 0, 0, 0);
        }
    }
#pragma unroll
    for (int mi = 0; mi < 4; mi++) {
#pragma unroll
      for (int r = 0; r < 4; r++) {
        int t = t0 + wm + mi * 16 + lq * 4 + r;
        bool ok = pass ? (t >= P) : (t < P);
        if (!ok) continue;
#pragma unroll
        for (int ni = 0; ni < 4; ni++)
          Y[((size_t)b * TT + t) * 512 + n0 + wn + ni * 16 + lm] = acc[mi][ni][r];
      }
    }
  }
}

// ------------- G, M, C_v Gram reductions via MFMA (partials, no atomics) -------------
__global__ __launch_bounds__(256) void build_gmc_mfma_k(
    const float* __restrict__ Y1, const float* __restrict__ Y2,
    const int* __restrict__ pref,
    float* __restrict__ Gp, float* __restrict__ Mp, float* __restrict__ Cp) {
  int P = pref[0]; P = P < 1 ? 1 : (P > TT - 1 ? TT - 1 : P);
  const int c  = blockIdx.x;
  const int bh = blockIdx.y;
  const int b = bh >> 4, h = bh & 15;
  const int chunk = (P + TCH - 1) / TCH;
  const int tb = c * chunk;
  const int te = min(tb + chunk, P);

  __shared__ __align__(16) unsigned short kCh[32 * 136], kCl[32 * 136];
  __shared__ __align__(16) unsigned short kPh[32 * 136], kPl[32 * 136];
  __shared__ __align__(16) unsigned short vTh[64 * 136], vTl[64 * 136];

  const int tid = threadIdx.x;
  const int wid = tid >> 6, lane = tid & 63;
  const int lm = lane & 15, lq = lane >> 4;

  f4v acc[4];
#pragma unroll
  for (int i = 0; i < 4; i++) acc[i] = (f4v){0.f, 0.f, 0.f, 0.f};

  for (int t0 = tb; t0 < te; t0 += 128) {
    const int len = (te - t0 < 128) ? (te - t0) : 128;
    __syncthreads();
    // stage keys: rows 0..128 map t = t0-1+row; kC[u=row-1] current, kP[u=row] prev
    for (int e = tid; e < 129 * 8; e += 256) {
      int row = e >> 3, j4 = (e & 7) << 2;
      int t = t0 - 1 + row;
      float4 kv = make_float4(0.f, 0.f, 0.f, 0.f);
      if (row <= len && t >= 0)
        kv = *(const float4*)&Y1[((size_t)b * TT + t) * 512 + h * 32 + j4];
      unsigned short hh[4], ll[4];
      split_bf16(kv.x, hh[0], ll[0]); split_bf16(kv.y, hh[1], ll[1]);
      split_bf16(kv.z, hh[2], ll[2]); split_bf16(kv.w, hh[3], ll[3]);
      if (row >= 1) {
#pragma unroll
        for (int q = 0; q < 4; q++) {
          kCh[(j4 + q) * 136 + row - 1] = hh[q];
          kCl[(j4 + q) * 136 + row - 1] = ll[q];
        }
      }
      if (row < 128) {
#pragma unroll
        for (int q = 0; q < 4; q++) {
          kPh[(j4 + q) * 136 + row] = hh[q];
          kPl[(j4 + q) * 136 + row] = ll[q];
        }
      }
    }
    // stage values: v_t[d] at u = row
    for (int e = tid; e < 128 * 16; e += 256) {
      int row = e >> 4, dj = (e & 15) << 2;
      int t = t0 + row;
      float4 vv = make_float4(0.f, 0.f, 0.f, 0.f);
      if (row < len)
        vv = *(const float4*)&Y2[((size_t)b * P + t) * 1024 + h * 64 + dj];
      unsigned short hh[4], ll[4];
      split_bf16(vv.x, hh[0], ll[0]); split_bf16(vv.y, hh[1], ll[1]);
      split_bf16(vv.z, hh[2], ll[2]); split_bf16(vv.w, hh[3], ll[3]);
#pragma unroll
      for (int q = 0; q < 4; q++) {
        vTh[(dj + q) * 136 + row] = hh[q];
        vTl[(dj + q) * 136 + row] = ll[q];
      }
    }
    __syncthreads();

#pragma unroll
    for (int kk = 0; kk < 128; kk += 32) {
      const int off = kk + lq * 8;
      if (wid == 0) {
        s8v h0 = *(const s8v*)&kCh[(0 + lm) * 136 + off];
        s8v h1 = *(const s8v*)&kCh[(16 + lm) * 136 + off];
        s8v l0 = *(const s8v*)&kCl[(0 + lm) * 136 + off];
        s8v l1 = *(const s8v*)&kCl[(16 + lm) * 136 + off];
        acc[0] = __builtin_amdgcn_mfma_f32_16x16x32_bf16(h0, h0, acc[0], 0, 0, 0);
        acc[0] = __builtin_amdgcn_mfma_f32_16x16x32_bf16(h0, l0, acc[0], 0, 0, 0);
        acc[0] = __builtin_amdgcn_mfma_f32_16x16x32_bf16(l0, h0, acc[0], 0, 0, 0);
        acc[1] = __builtin_amdgcn_mfma_f32_16x16x32_bf16(h0, h1, acc[1], 0, 0, 0);
        acc[1] = __builtin_amdgcn_mfma_f32_16x16x32_bf16(h0, l1, acc[1], 0, 0, 0);
        acc[1] = __builtin_amdgcn_mfma_f32_16x16x32_bf16(l0, h1, acc[1], 0, 0, 0);
        acc[2] = __builtin_amdgcn_mfma_f32_16x16x32_bf16(h1, h0, acc[2], 0, 0, 0);
        acc[2] = __builtin_amdgcn_mfma_f32_16x16x32_bf16(h1, l0, acc[2], 0, 0, 0);
        acc[2] = __builtin_amdgcn_mfma_f32_16x16x32_bf16(l1, h0, acc[2], 0, 0, 0);
        acc[3] = __builtin_amdgcn_mfma_f32_16x16x32_bf16(h1, h1, acc[3], 0, 0, 0);
        acc[3] = __builtin_amdgcn_mfma_f32_16x16x32_bf16(h1, l1, acc[3], 0, 0, 0);
        acc[3] = __builtin_amdgcn_mfma_f32_16x16x32_bf16(l1, h1, acc[3], 0, 0, 0);
      } else if (wid == 1) {
        s8v ah0 = *(const s8v*)&kCh[(0 + lm) * 136 + off];
        s8v ah1 = *(const s8v*)&kCh[(16 + lm) * 136 + off];
        s8v al0 = *(const s8v*)&kCl[(0 + lm) * 136 + off];
        s8v al1 = *(const s8v*)&kCl[(16 + lm) * 136 + off];
        s8v bh0 = *(const s8v*)&kPh[(0 + lm) * 136 + off];
        s8v bh1 = *(const s8v*)&kPh[(16 + lm) * 136 + off];
        s8v bl0 = *(const s8v*)&kPl[(0 + lm) * 136 + off];
        s8v bl1 = *(const s8v*)&kPl[(16 + lm) * 136 + off];
        acc[0] = __builtin_amdgcn_mfma_f32_16x16x32_bf16(ah0, bh0, acc[0], 0, 0, 0);
        acc[0] = __builtin_amdgcn_mfma_f32_16x16x32_bf16(ah0, bl0, acc[0], 0, 0, 0);
        acc[0] = __builtin_amdgcn_mfma_f32_16x16x32_bf16(al0, bh0, acc[0], 0, 0, 0);
        acc[1] = __builtin_amdgcn_mfma_f32_16x16x32_bf16(ah0, bh1, acc[1], 0, 0, 0);
        acc[1] = __builtin_amdgcn_mfma_f32_16x16x32_bf16(ah0, bl1, acc[1], 0, 0, 0);
        acc[1] = __builtin_amdgcn_mfma_f32_16x16x32_bf16(al0, bh1, acc[1], 0, 0, 0);
        acc[2] = __builtin_amdgcn_mfma_f32_16x16x32_bf16(ah1, bh0, acc[2], 0, 0, 0);
        acc[2] = __builtin_amdgcn_mfma_f32_16x16x32_bf16(ah1, bl0, acc[2], 0, 0, 0);
        acc[2] = __builtin_amdgcn_mfma_f32_16x16x32_bf16(al1, bh0, acc[2], 0, 0, 0);
        acc[3] = __builtin_amdgcn_mfma_f32_16x16x32_bf16(ah1, bh1, acc[3], 0, 0, 0);
        acc[3] = __builtin_amdgcn_mfma_f32_16x16x32_bf16(ah1, bl1, acc[3], 0, 0, 0);
        acc[3] = __builtin_amdgcn_mfma_f32_16x16x32_bf16(al1, bh1, acc[3], 0, 0, 0);
      } else {
        const int d0 = (wid - 2) * 32;
        s8v vh0 = *(const s8v*)&vTh[(d0 + lm) * 136 + off];
        s8v vh1 = *(const s8v*)&vTh[(d0 + 16 + lm) * 136 + off];
        s8v vl0 = *(const s8v*)&vTl[(d0 + lm) * 136 + off];
        s8v vl1 = *(const s8v*)&vTl[(d0 + 16 + lm) * 136 + off];
        s8v kh0 = *(const s8v*)&kCh[(0 + lm) * 136 + off];
        s8v kh1 = *(const s8v*)&kCh[(16 + lm) * 136 + off];
        s8v kl0 = *(const s8v*)&kCl[(0 + lm) * 136 + off];
        s8v kl1 = *(const s8v*)&kCl[(16 + lm) * 136 + off];
        acc[0] = __builtin_amdgcn_mfma_f32_16x16x32_bf16(vh0, kh0, acc[0], 0, 0, 0);
        acc[0] = __builtin_amdgcn_mfma_f32_16x16x32_bf16(vh0, kl0, acc[0], 0, 0, 0);
        acc[0] = __builtin_amdgcn_mfma_f32_16x16x32_bf16(vl0, kh0, acc[0], 0, 0, 0);
        acc[1] = __builtin_amdgcn_mfma_f32_16x16x32_bf16(vh0, kh1, acc[1], 0, 0, 0);
        acc[1] = __builtin_amdgcn_mfma_f32_16x16x32_bf16(vh0, kl1, acc[1], 0, 0, 0);
        acc[1] = __builtin_amdgcn_mfma_f32_16x16x32_bf16(vl0, kh1, acc[1], 0, 0, 0);
        acc[2] = __builtin_amdgcn_mfma_f32_16x16x32_bf16(vh1, kh0, acc[2], 0, 0, 0);
        acc[2] = __builtin_amdgcn_mfma_f32_16x16x32_bf16(vh1, kl0, acc[2], 0, 0, 0);
        acc[2] = __builtin_amdgcn_mfma_f32_16x16x32_bf16(vl1, kh0, acc[2], 0, 0, 0);
        acc[3] = __builtin_amdgcn_mfma_f32_16x16x32_bf16(vh1, kh1, acc[3], 0, 0, 0);
        acc[3] = __builtin_amdgcn_mfma_f32_16x16x32_bf16(vh1, kl1, acc[3], 0, 0, 0);
        acc[3] = __builtin_amdgcn_mfma_f32_16x16x32_bf16(vl1, kh1, acc[3], 0, 0, 0);
      }
    }
  }

  // write partials (D layout: col = lm, row = lq*4 + r)
  if (wid < 2) {
    float* dst = (wid == 0 ? Gp : Mp) + (size_t)(c * 64 + bh) * 1024;
#pragma unroll
    for (int t = 0; t < 4; t++) {
      int i0 = (t >> 1) * 16, j0 = (t & 1) * 16;
#pragma unroll
      for (int r = 0; r < 4; r++)
        dst[(i0 + lq * 4 + r) * 32 + j0 + lm] = acc[t][r];
    }
  } else {
    float* dst = Cp + (size_t)(c * 64 + bh) * 2048;
#pragma unroll
    for (int t = 0; t < 4; t++) {
      int d0 = (wid - 2) * 32 + (t >> 1) * 16, j0 = (t & 1) * 16;
#pragma unroll
      for (int r = 0; r < 4; r++)
        dst[(d0 + lq * 4 + r) * 32 + j0 + lm] = acc[t][r];
    }
  }
}

// ------- per-(b,h) operator: chol, G^{-1}, A_w, sigma, F = Cv*Gi*(s*M*Gi)^4 -------
__global__ __launch_bounds__(256) void solve_op_k(
    const float* __restrict__ Gp, const float* __restrict__ Mp,
    const float* __restrict__ Cp, const float* __restrict__ lridge,
    const float* __restrict__ lgamma, float* __restrict__ Ft) {
  __shared__ float Gs[32 * 33];
  __shared__ float Ms[32 * 32];
  __shared__ float Gi[32 * 32];
  __shared__ float W1[32 * 33];
  __shared__ float Aw[32 * 33];
  __shared__ float Nn[32 * 32];
  __shared__ float N2[32 * 32];
  __shared__ float T1[32 * 32];
  __shared__ float Cs[64 * 32];
  __shared__ float red[256];
  __shared__ float vv[32], uu[32];
  const int bh = blockIdx.x;
  const int tid = threadIdx.x;
  const float ridge = expf(lridge[0]);

  for (int e = tid; e < 1024; e += 256) {
    int i = e >> 5, j = e & 31;
    float g = 0.f, m = 0.f;
#pragma unroll
    for (int cc = 0; cc < TCH; cc++) {
      g += Gp[(size_t)(cc * 64 + bh) * 1024 + e];
      m += Mp[(size_t)(cc * 64 + bh) * 1024 + e];
    }
    if (i == j) g += ridge;
    Gs[i * 33 + j] = g;
    Ms[e] = m;
  }
  for (int e = tid; e < 2048; e += 256) {
    float s = 0.f;
#pragma unroll
    for (int cc = 0; cc < TCH; cc++) s += Cp[(size_t)(cc * 64 + bh) * 2048 + e];
    Cs[e] = s;
  }
  __syncthreads();

  for (int j = 0; j < 32; j++) {
    float d = Gs[j * 33 + j];
    __syncthreads();
    float inv = 1.0f / sqrtf(d);
    if (tid >= j && tid < 32) Gs[tid * 33 + j] *= inv;
    __syncthreads();
    int w = 31 - j;
    for (int e = tid; e < w * w; e += 256) {
      int i = j + 1 + e / w, k = j + 1 + e % w;
      Gs[i * 33 + k] -= Gs[i * 33 + j] * Gs[k * 33 + j];
    }
    __syncthreads();
  }

  if (tid < 32) {
    const int c = tid;
    for (int i = 0; i < 32; i++) W1[i * 33 + c] = (i == c) ? 1.0f : 0.0f;
    for (int i = 0; i < 32; i++) {
      float s = W1[i * 33 + c];
      for (int j = 0; j < i; j++) s -= Gs[i * 33 + j] * W1[j * 33 + c];
      W1[i * 33 + c] = s / Gs[i * 33 + i];
    }
    for (int i = 31; i >= 0; i--) {
      float s = W1[i * 33 + c];
      for (int j = i + 1; j < 32; j++) s -= Gs[j * 33 + i] * W1[j * 33 + c];
      W1[i * 33 + c] = s / Gs[i * 33 + i];
    }
    for (int i = 0; i < 32; i++) Gi[i * 32 + c] = W1[i * 33 + c];
  }
  __syncthreads();
  if (tid < 32) {
    const int c = tid;
    for (int i = 0; i < 32; i++) {
      float s = Ms[i * 32 + c];
      for (int j = 0; j < i; j++) s -= Gs[i * 33 + j] * W1[j * 33 + c];
      W1[i * 33 + c] = s / Gs[i * 33 + i];
    }
  }
  __syncthreads();
  if (tid < 32) {
    const int c = tid;
    for (int i = 0; i < 32; i++) {
      float s = W1[c * 33 + i];
      for (int j = 0; j < i; j++) s -= Gs[i * 33 + j] * Aw[j * 33 + c];
      Aw[i * 33 + c] = s / Gs[i * 33 + i];
    }
  }
  __syncthreads();

  float s0 = 0.0f;
  for (int e = tid; e < 1024; e += 256) {
    float a = Aw[(e >> 5) * 33 + (e & 31)];
    s0 += a * a;
  }
  red[tid] = s0;
  __syncthreads();
  for (int off = 128; off > 0; off >>= 1) {
    if (tid < off) red[tid] += red[tid + off];
    __syncthreads();
  }
  float frob2 = red[0];
  float sigma;
  if (frob2 <= 1.0f) {
    sigma = sqrtf(frob2);
  } else {
    if (tid < 32) vv[tid] = 1.0f + 0.001f * (float)tid;
    __syncthreads();
    for (int it = 0; it < 64; it++) {
      if (tid < 32) {
        float s = 0;
        for (int j = 0; j < 32; j++) s += Aw[tid * 33 + j] * vv[j];
        uu[tid] = s;
      }
      __syncthreads();
      if (tid == 0) {
        float n = 0;
        for (int j = 0; j < 32; j++) n += uu[j] * uu[j];
        red[0] = sqrtf(n);
      }
      __syncthreads();
      float nu = fmaxf(red[0], 1e-30f);
      if (tid < 32) uu[tid] /= nu;
      __syncthreads();
      if (tid < 32) {
        float s = 0;
        for (int j = 0; j < 32; j++) s += Aw[j * 33 + tid] * uu[j];
        vv[tid] = s;
      }
      __syncthreads();
      if (tid == 0) {
        float n = 0;
        for (int j = 0; j < 32; j++) n += vv[j] * vv[j];
        red[0] = sqrtf(n);
      }
      __syncthreads();
      float nv = fmaxf(red[0], 1e-30f);
      if (tid < 32) vv[tid] /= nv;
      __syncthreads();
    }
    sigma = red[0];
  }
  float gamma_c = fminf(expf(lgamma[0]), 1.0f);
  float scale = gamma_c / fmaxf(fmaxf(sigma, 1e-8f), 1.0f);

  for (int e = tid; e < 1024; e += 256) {
    int i = e >> 5, c = e & 31;
    float s = 0;
#pragma unroll
    for (int k = 0; k < 32; k++) s += Ms[i * 32 + k] * Gi[k * 32 + c];
    Nn[e] = scale * s;
  }
  __syncthreads();
  for (int e = tid; e < 1024; e += 256) {
    int i = e >> 5, c = e & 31;
    float s = 0;
#pragma unroll
    for (int k = 0; k < 32; k++) s += Nn[i * 32 + k] * Nn[k * 32 + c];
    N2[e] = s;
  }
  __syncthreads();
  for (int e = tid; e < 1024; e += 256) {
    int i = e >> 5, c = e & 31;
    float s = 0;
#pragma unroll
    for (int k = 0; k < 32; k++) s += N2[i * 32 + k] * N2[k * 32 + c];
    Ms[e] = s;
  }
  __syncthreads();
  for (int e = tid; e < 1024; e += 256) {
    int i = e >> 5, c = e & 31;
    float s = 0;
#pragma unroll
    for (int k = 0; k < 32; k++) s += Gi[i * 32 + k] * Ms[k * 32 + c];
    T1[e] = s;
  }
  __syncthreads();
  for (int e = tid; e < 2048; e += 256) {
    int j = e >> 6, d = e & 63;
    float s = 0;
#pragma unroll
    for (int k = 0; k < 32; k++) s += Cs[d * 32 + k] * T1[k * 32 + j];
    Ft[(size_t)bh * 2048 + e] = s;
  }
}

// ------------- apply F^T per (head, 128-token chunk) -> full_hi (bf16) -------------
__global__ __launch_bounds__(256) void apply_k(const float* __restrict__ Y1,
                                               const float* __restrict__ Ft,
                                               unsigned short* __restrict__ FH) {
  __shared__ float xs[128 * 32];
  const int h = blockIdx.y;
  const int r0 = blockIdx.x * 128;
  const int bh = (r0 >> 12) * NH + h;
  const int tid = threadIdx.x;
  const int d = tid & 63, t0 = tid >> 6;
  float fcol[32];
  const float* fb = &Ft[(size_t)bh * 2048 + d];
#pragma unroll
  for (int j = 0; j < 32; j++) fcol[j] = fb[j * 64];
  for (int e = tid; e < 1024; e += 256) {
    int row = e >> 3, j4 = (e & 7) << 2;
    *(float4*)&xs[row * 32 + j4] =
        *(const float4*)&Y1[((size_t)(r0 + row)) * 512 + h * 32 + j4];
  }
  __syncthreads();
  for (int tl = t0; tl < 128; tl += 4) {
    float s = 0;
#pragma unroll
    for (int j = 0; j < 32; j++) s += xs[tl * 32 + j] * fcol[j];
    FH[((size_t)(r0 + tl)) * 1024 + h * 64 + d] = bf16_rne(s);
  }
}

// ------------- output GEMM (MFMA): out = sg * full @ Wo ; A=hi, B=hi+lo -------------
// all operands pre-formatted bf16 -> full global_load_lds staging (m97 structure)
__global__ __launch_bounds__(256) void gemm_out_k(
    const unsigned short* __restrict__ FH,
    const unsigned short* __restrict__ WThi, const unsigned short* __restrict__ WTlo,
    const float* __restrict__ alpha, float* __restrict__ out) {
  int xx, yy, zz;
  xcd_swz(8, 128, xx, yy, zz);
  const int m0 = yy * 128;
  const int n0 = xx * 128;
  __shared__ __align__(16) unsigned short Ah[128 * 32];
  __shared__ __align__(16) unsigned short Bh[128 * 32], Bl[128 * 32];
  const int tid = threadIdx.x;
  const int lane = tid & 63;
  const int wid  = tid >> 6;
  const int wm = (wid >> 1) * 64, wn = (wid & 1) * 64;
  const int lm = lane & 15, lq = lane >> 4;
  const int srow = lane >> 2, scol = (lane & 3) << 3;
  f4v acc[4][4];
#pragma unroll
  for (int i = 0; i < 4; i++)
#pragma unroll
    for (int j = 0; j < 4; j++) acc[i][j] = (f4v){0.f, 0.f, 0.f, 0.f};

  for (int kt = 0; kt < D_MODEL; kt += 32) {
    __syncthreads();
#pragma unroll
    for (int s = 0; s < 2; s++) {
      int seg = wid * 2 + s;
      int row = seg * 16 + srow;
      gll16(&Ah[seg * 512], &FH  [(size_t)(m0 + row) * 1024 + kt + scol]);
      gll16(&Bh[seg * 512], &WThi[(size_t)(n0 + row) * 1024 + kt + scol]);
      gll16(&Bl[seg * 512], &WTlo[(size_t)(n0 + row) * 1024 + kt + scol]);
    }
    __syncthreads();
    s8v ah[4], bh[4], bl[4];
#pragma unroll
    for (int i = 0; i < 4; i++) {
      ah[i] = *(const s8v*)&Ah[(wm + i * 16 + lm) * 32 + lq * 8];
      bh[i] = *(const s8v*)&Bh[(wn + i * 16 + lm) * 32 + lq * 8];
      bl[i] = *(const s8v*)&Bl[(wn + i * 16 + lm) * 32 + lq * 8];
    }
#pragma unroll
    for (int mi = 0; mi < 4; mi++)
#pragma unroll
      for (int ni = 0; ni < 4; ni++) {
        acc[mi][ni] = __builtin_amdgcn_mfma_f32_16x16x32_bf16(ah[mi], bh[ni], acc[mi][ni], 0, 0, 0);
        acc[mi][ni] = __builtin_amdgcn_mfma_f32_16x16x32_bf16(ah[mi], bl[ni], acc[mi][ni], 0, 0, 0);
      }
  }
  float sg = 1.0f / (1.0f + expf(-alpha[0]));
#pragma unroll
  for (int mi = 0; mi < 4; mi++)
#pragma unroll
    for (int r = 0; r < 4; r++) {
      size_t orow = (size_t)(m0 + wm + mi * 16 + lq * 4 + r);
#pragma unroll
      for (int ni = 0; ni < 4; ni++)
        out[orow * 1024 + n0 + wn + ni * 16 + lm] = sg * acc[mi][ni][r];
    }
}

extern "C" void kernel_launch(void* const* d_in, const int* in_sizes, int n_in,
                              void* d_out, int out_size, void* d_ws, size_t ws_size,
                              hipStream_t stream) {
  const float* X      = (const float*)d_in[0];
  const float* Wk     = (const float*)d_in[1];
  const float* Wq     = (const float*)d_in[2];
  const float* Wv     = (const float*)d_in[3];
  const float* Wo     = (const float*)d_in[4];
  const float* lng    = (const float*)d_in[5];
  const float* lnb    = (const float*)d_in[6];
  const float* alpha  = (const float*)d_in[7];
  const float* lridge = (const float*)d_in[8];
  const float* lgamma = (const float*)d_in[9];
  const int*   pref   = (const int*)d_in[10];
  float* out = (float*)d_out;
  char* ws = (char*)d_ws;
  float* stats = (float*)(ws + OFF_STATS);
  float* Gp    = (float*)(ws + OFF_GP);
  float* Mp    = (float*)(ws + OFF_MP);
  float* Cp    = (float*)(ws + OFF_CP);
  float* Ft    = (float*)(ws + OFF_FT);
  unsigned short* WKH = (unsigned short*)(ws + OFF_WKH);
  unsigned short* WKL = (unsigned short*)(ws + OFF_WKL);
  unsigned short* WQH = (unsigned short*)(ws + OFF_WQH);
  unsigned short* WQL = (unsigned short*)(ws + OFF_WQL);
  unsigned short* WVH = (unsigned short*)(ws + OFF_WVH);
  unsigned short* WVL = (unsigned short*)(ws + OFF_WVL);
  unsigned short* WOH = (unsigned short*)(ws + OFF_WOH);
  unsigned short* WOL = (unsigned short*)(ws + OFF_WOL);
  float* Y1 = (float*)(ws + OFF_Y1);
  float* Y2 = (float*)(ws + OFF_Y2);
  unsigned short* FH = (unsigned short*)(ws + OFF_FH);

  ln_stats_k<<<16384, 256, 0, stream>>>(X, stats);
  prep_w_k<<<dim3(16, 32), 256, 0, stream>>>(Wk, 512, WKH, WKL);
  prep_w_k<<<dim3(16, 32), 256, 0, stream>>>(Wq, 512, WQH, WQL);
  prep_w_k<<<dim3(32, 32), 256, 0, stream>>>(Wv, 1024, WVH, WVL);
  prep_w_k<<<dim3(32, 32), 256, 0, stream>>>(Wo, 1024, WOH, WOL);
  gemm_kq_k<<<dim3(4, 32, NB), 256, 0, stream>>>(X, stats, lng, lnb, WKH, WKL, WQH, WQL, pref, Y1);
  gemm_proj_k<<<dim3(8, 32, NB), 256, 0, stream>>>(X, stats, lng, lnb, WVH, WVL, 1024, pref, 2, Y2);
  build_gmc_mfma_k<<<dim3(TCH, 64), 256, 0, stream>>>(Y1, Y2, pref, Gp, Mp, Cp);
  solve_op_k<<<64, 256, 0, stream>>>(Gp, Mp, Cp, lridge, lgamma, Ft);
  apply_k<<<dim3(128, NH), 256, 0, stream>>>(Y1, Ft, FH);
  gemm_out_k<<<dim3(8, 128), 256, 0, stream>>>(FH, WOH, WOL, alpha, out);
}

// Round 4
// 461.759 us; speedup vs baseline: 1.4262x; 1.0122x over previous
//
#include <hip/hip_runtime.h>
#include <math.h>

#define D_MODEL 1024
#define TT 4096
#define NB 4
#define NH 16
#define TCH 8

typedef __attribute__((ext_vector_type(8))) short s8v;
typedef __attribute__((ext_vector_type(4))) float f4v;
typedef __attribute__((ext_vector_type(8))) unsigned short u16x8;

// ---- workspace layout (bytes); peak ~88 MB (proven budget 100 MB) ----
#define OFF_STATS ((size_t)0)
#define OFF_GP    ((size_t)(1) << 20)    // 8*64*1024*4 = 2 MB partials
#define OFF_MP    ((size_t)(3) << 20)    // 2 MB
#define OFF_CP    ((size_t)(5) << 20)    // 8*64*2048*4 = 4 MB
#define OFF_FT    ((size_t)(9) << 20)    // 512 KB
#define OFF_WKH   ((size_t)(10) << 20)
#define OFF_WKL   ((size_t)(11) << 20)
#define OFF_WQH   ((size_t)(12) << 20)
#define OFF_WQL   ((size_t)(13) << 20)
#define OFF_WVH   ((size_t)(14) << 20)
#define OFF_WVL   ((size_t)(16) << 20)
#define OFF_WOH   ((size_t)(18) << 20)
#define OFF_WOL   ((size_t)(20) << 20)
#define OFF_Y1    ((size_t)(22) << 20)   // 32 MB
#define OFF_Y2    ((size_t)(54) << 20)   // P*NB*1024*4; FH overlays after build_gmc
#define OFF_FH    OFF_Y2

__device__ __forceinline__ unsigned short bf16_rne(float x) {
  unsigned u = __float_as_uint(x);
  return (unsigned short)((u + 0x7fffu + ((u >> 16) & 1u)) >> 16);
}
__device__ __forceinline__ void split_bf16(float x, unsigned short& h, unsigned short& l) {
  unsigned u = __float_as_uint(x);
  unsigned r = (u + 0x7fffu + ((u >> 16) & 1u)) & 0xffff0000u;
  h = (unsigned short)(r >> 16);
  float res = x - __uint_as_float(r);
  l = bf16_rne(res);
}

// async global->LDS, 16 B per lane; lds base must be wave-uniform (HW adds lane*16)
__device__ __forceinline__ void gll16(unsigned short* lds, const unsigned short* g) {
  __builtin_amdgcn_global_load_lds(
      (__attribute__((address_space(1))) void*)(void*)(g),
      (__attribute__((address_space(3))) void*)(lds), 16, 0, 0);
}

// bijective XCD swizzle: the gx blocks sharing one (y,z) land consecutively on ONE
// XCD; (y,z) values strided by 8 across XCDs (keeps P-masked kernels balanced).
__device__ __forceinline__ void xcd_swz(int gx, int gy, int& x, int& y, int& z) {
  int wg = blockIdx.x + gx * (blockIdx.y + gy * blockIdx.z);
  int k = wg & 7, j = wg >> 3;
  x = j % gx;
  int yz = k + ((j / gx) << 3);
  y = yz % gy;
  z = yz / gy;
}

// ---------------- LayerNorm statistics: one block per row ----------------
__global__ __launch_bounds__(256) void ln_stats_k(const float* __restrict__ X,
                                                  float* __restrict__ stats) {
  int r = blockIdx.x;
  const float4 v = ((const float4*)(X + (size_t)r * D_MODEL))[threadIdx.x];
  float s  = v.x + v.y + v.z + v.w;
  float ss = v.x * v.x + v.y * v.y + v.z * v.z + v.w * v.w;
#pragma unroll
  for (int off = 32; off > 0; off >>= 1) {
    s  += __shfl_down(s, off, 64);
    ss += __shfl_down(ss, off, 64);
  }
  __shared__ float as_[4], bs_[4];
  int w = threadIdx.x >> 6, lane = threadIdx.x & 63;
  if (lane == 0) { as_[w] = s; bs_[w] = ss; }
  __syncthreads();
  if (threadIdx.x == 0) {
    float S  = as_[0] + as_[1] + as_[2] + as_[3];
    float SS = bs_[0] + bs_[1] + bs_[2] + bs_[3];
    float mu  = S * (1.0f / D_MODEL);
    float var = SS * (1.0f / D_MODEL) - mu * mu;
    stats[2 * (size_t)r]     = mu;
    stats[2 * (size_t)r + 1] = 1.0f / sqrtf(var + 1e-5f);
  }
}

// ------- prep: transpose W[K][N] -> WT_hi/lo [N][K] bf16 split -------
// swz=1: XOR-swizzle 16B chunk index with row&7 within each 64-col group
// (consumed by gemm_out_k's linear global_load_lds + swizzled ds_read).
__global__ __launch_bounds__(256) void prep_w_k(const float* __restrict__ W, int N,
                                                unsigned short* __restrict__ Thi,
                                                unsigned short* __restrict__ Tlo,
                                                int swz) {
  __shared__ float tileT[32 * 33];
  const int n0 = blockIdx.x * 32, k0 = blockIdx.y * 32;
  const int tid = threadIdx.x;
  {
    int k_l = tid >> 3, n4 = (tid & 7) << 2;
    float4 v = *(const float4*)&W[(size_t)(k0 + k_l) * N + n0 + n4];
    tileT[(n4 + 0) * 33 + k_l] = v.x;
    tileT[(n4 + 1) * 33 + k_l] = v.y;
    tileT[(n4 + 2) * 33 + k_l] = v.z;
    tileT[(n4 + 3) * 33 + k_l] = v.w;
  }
  __syncthreads();
  {
    int n_l = tid >> 3, k4 = (tid & 7) << 2;
    unsigned short h[4], l[4];
#pragma unroll
    for (int i = 0; i < 4; i++) split_bf16(tileT[n_l * 33 + k4 + i], h[i], l[i]);
    int kc = k0 + k4;
    int col = swz ? ((kc & ~63) | ((((kc >> 3) & 7) ^ (n_l & 7)) << 3) | (kc & 7)) : kc;
    *(ushort4*)&Thi[(size_t)(n0 + n_l) * 1024 + col] = make_ushort4(h[0], h[1], h[2], h[3]);
    *(ushort4*)&Tlo[(size_t)(n0 + n_l) * 1024 + col] = make_ushort4(l[0], l[1], l[2], l[3]);
  }
}

// ------- fused LN + projection GEMM, split-bf16 MFMA (3 products) -------
// A reg-staged (LN fusion); B via global_load_lds width-16, linear [128][32] LDS.
// mode 2: rows t<P, Wv -> Y2 compact
__global__ __launch_bounds__(256) void gemm_proj_k(
    const float* __restrict__ X, const float* __restrict__ stats,
    const float* __restrict__ lng, const float* __restrict__ lnb,
    const unsigned short* __restrict__ WThi, const unsigned short* __restrict__ WTlo,
    int Nw, const int* __restrict__ pref, int mode, float* __restrict__ Y) {
  int P = pref[0]; P = P < 1 ? 1 : (P > TT - 1 ? TT - 1 : P);
  int xx, yy, zz;
  xcd_swz(8, 32, xx, yy, zz);
  const int b  = zz;
  const int t0 = yy * 128;
  const int n0 = xx * 128;
  if (mode == 1) { if (t0 + 128 <= P) return; }
  else           { if (t0 >= P) return; }
  const int row0 = b * TT + t0;
  __shared__ __align__(16) unsigned short Ah[128 * 40], Al[128 * 40];
  __shared__ __align__(16) unsigned short Bh[128 * 32], Bl[128 * 32];
  __shared__ float mus[128], rss[128];
  const int tid = threadIdx.x;
  if (tid < 128) {
    mus[tid] = stats[2 * (size_t)(row0 + tid)];
    rss[tid] = stats[2 * (size_t)(row0 + tid) + 1];
  }
  const int lane = tid & 63;
  const int wid  = tid >> 6;
  const int wm = (wid >> 1) * 64, wn = (wid & 1) * 64;
  const int lm = lane & 15, lq = lane >> 4;
  const int srow = lane >> 2, scol = (lane & 3) << 3;  // staging: 16 rows x 4 chunks
  f4v acc[4][4];
#pragma unroll
  for (int i = 0; i < 4; i++)
#pragma unroll
    for (int j = 0; j < 4; j++) acc[i][j] = (f4v){0.f, 0.f, 0.f, 0.f};

  for (int kt = 0; kt < D_MODEL; kt += 32) {
    __syncthreads();
#pragma unroll
    for (int s = 0; s < 2; s++) {
      int seg = wid * 2 + s;
      int brow = n0 + seg * 16 + srow;
      gll16(&Bh[seg * 512], &WThi[(size_t)brow * 1024 + kt + scol]);
      gll16(&Bl[seg * 512], &WTlo[(size_t)brow * 1024 + kt + scol]);
    }
#pragma unroll
    for (int q = 0; q < 2; q++) {
      int c = tid * 2 + q;
      int m = c >> 2, k8 = (c & 3) << 3;
      const float* src = &X[(size_t)(row0 + m) * D_MODEL + kt + k8];
      float mu = mus[m], rs = rss[m];
      u16x8 hv, lv;
#pragma unroll
      for (int i = 0; i < 8; i++) {
        float nv = (src[i] - mu) * rs * lng[kt + k8 + i] + lnb[kt + k8 + i];
        unsigned short h, l;
        split_bf16(nv, h, l);
        hv[i] = h; lv[i] = l;
      }
      *(u16x8*)&Ah[m * 40 + k8] = hv;
      *(u16x8*)&Al[m * 40 + k8] = lv;
    }
    __syncthreads();
    s8v ah[4], al[4], bh[4], bl[4];
#pragma unroll
    for (int i = 0; i < 4; i++) {
      int ar = (wm + i * 16 + lm) * 40 + lq * 8;
      int br = (wn + i * 16 + lm) * 32 + lq * 8;
      ah[i] = *(const s8v*)&Ah[ar];
      al[i] = *(const s8v*)&Al[ar];
      bh[i] = *(const s8v*)&Bh[br];
      bl[i] = *(const s8v*)&Bl[br];
    }
#pragma unroll
    for (int mi = 0; mi < 4; mi++)
#pragma unroll
      for (int ni = 0; ni < 4; ni++) {
        acc[mi][ni] = __builtin_amdgcn_mfma_f32_16x16x32_bf16(ah[mi], bh[ni], acc[mi][ni], 0, 0, 0);
        acc[mi][ni] = __builtin_amdgcn_mfma_f32_16x16x32_bf16(ah[mi], bl[ni], acc[mi][ni], 0, 0, 0);
        acc[mi][ni] = __builtin_amdgcn_mfma_f32_16x16x32_bf16(al[mi], bh[ni], acc[mi][ni], 0, 0, 0);
      }
  }
#pragma unroll
  for (int mi = 0; mi < 4; mi++) {
#pragma unroll
    for (int r = 0; r < 4; r++) {
      int t = t0 + wm + mi * 16 + lq * 4 + r;
      bool ok = (mode == 1) ? (t >= P) : (t < P);
      if (!ok) continue;
      size_t orow = (mode == 2) ? ((size_t)b * P + t) : ((size_t)b * TT + t);
#pragma unroll
      for (int ni = 0; ni < 4; ni++)
        Y[orow * Nw + n0 + wn + ni * 16 + lm] = acc[mi][ni][r];
    }
  }
}

// ------- merged K/Q projection: one launch, all t-blocks active -------
__global__ __launch_bounds__(256) void gemm_kq_k(
    const float* __restrict__ X, const float* __restrict__ stats,
    const float* __restrict__ lng, const float* __restrict__ lnb,
    const unsigned short* __restrict__ KH, const unsigned short* __restrict__ KL,
    const unsigned short* __restrict__ QH, const unsigned short* __restrict__ QL,
    const int* __restrict__ pref, float* __restrict__ Y) {
  int P = pref[0]; P = P < 1 ? 1 : (P > TT - 1 ? TT - 1 : P);
  int xx, yy, zz;
  xcd_swz(4, 32, xx, yy, zz);
  const int b  = zz;
  const int t0 = yy * 128;
  const int n0 = xx * 128;
  const int row0 = b * TT + t0;
  const bool hasK = (t0 < P);
  const bool hasQ = (t0 + 128 > P);
  __shared__ __align__(16) unsigned short Ah[128 * 40], Al[128 * 40];
  __shared__ __align__(16) unsigned short Bh[128 * 32], Bl[128 * 32];
  __shared__ float mus[128], rss[128];
  const int tid = threadIdx.x;
  if (tid < 128) {
    mus[tid] = stats[2 * (size_t)(row0 + tid)];
    rss[tid] = stats[2 * (size_t)(row0 + tid) + 1];
  }
  const int lane = tid & 63;
  const int wid  = tid >> 6;
  const int wm = (wid >> 1) * 64, wn = (wid & 1) * 64;
  const int lm = lane & 15, lq = lane >> 4;
  const int srow = lane >> 2, scol = (lane & 3) << 3;

  for (int pass = 0; pass < 2; pass++) {
    if (pass == 0 && !hasK) continue;
    if (pass == 1 && !hasQ) continue;
    const unsigned short* WThi = pass ? QH : KH;
    const unsigned short* WTlo = pass ? QL : KL;
    f4v acc[4][4];
#pragma unroll
    for (int i = 0; i < 4; i++)
#pragma unroll
      for (int j = 0; j < 4; j++) acc[i][j] = (f4v){0.f, 0.f, 0.f, 0.f};

    for (int kt = 0; kt < D_MODEL; kt += 32) {
      __syncthreads();
#pragma unroll
      for (int s = 0; s < 2; s++) {
        int seg = wid * 2 + s;
        int brow = n0 + seg * 16 + srow;
        gll16(&Bh[seg * 512], &WThi[(size_t)brow * 1024 + kt + scol]);
        gll16(&Bl[seg * 512], &WTlo[(size_t)brow * 1024 + kt + scol]);
      }
#pragma unroll
      for (int q = 0; q < 2; q++) {
        int c = tid * 2 + q;
        int m = c >> 2, k8 = (c & 3) << 3;
        const float* src = &X[(size_t)(row0 + m) * D_MODEL + kt + k8];
        float mu = mus[m], rs = rss[m];
        u16x8 hv, lv;
#pragma unroll
        for (int i = 0; i < 8; i++) {
          float nv = (src[i] - mu) * rs * lng[kt + k8 + i] + lnb[kt + k8 + i];
          unsigned short h, l;
          split_bf16(nv, h, l);
          hv[i] = h; lv[i] = l;
        }
        *(u16x8*)&Ah[m * 40 + k8] = hv;
        *(u16x8*)&Al[m * 40 + k8] = lv;
      }
      __syncthreads();
      s8v ah[4], al[4], bh[4], bl[4];
#pragma unroll
      for (int i = 0; i < 4; i++) {
        int ar = (wm + i * 16 + lm) * 40 + lq * 8;
        int br = (wn + i * 16 + lm) * 32 + lq * 8;
        ah[i] = *(const s8v*)&Ah[ar];
        al[i] = *(const s8v*)&Al[ar];
        bh[i] = *(const s8v*)&Bh[br];
        bl[i] = *(const s8v*)&Bl[br];
      }
#pragma unroll
      for (int mi = 0; mi < 4; mi++)
#pragma unroll
        for (int ni = 0; ni < 4; ni++) {
          acc[mi][ni] = __builtin_amdgcn_mfma_f32_16x16x32_bf16(ah[mi], bh[ni], acc[mi][ni], 0, 0, 0);
          acc[mi][ni] = __builtin_amdgcn_mfma_f32_16x16x32_bf16(ah[mi], bl[ni], acc[mi][ni], 0, 0, 0);
          acc[mi][ni] = __builtin_amdgcn_mfma_f32_16x16x32_bf16(al[mi], bh[ni], acc[mi][ni], 0, 0, 0);
        }
    }
#pragma unroll
    for (int mi = 0; mi < 4; mi++) {
#pragma unroll
      for (int r = 0; r < 4; r++) {
        int t = t0 + wm + mi * 16 + lq * 4 + r;
        bool ok = pass ? (t >= P) : (t < P);
        if (!ok) continue;
#pragma unroll
        for (int ni = 0; ni < 4; ni++)
          Y[((size_t)b * TT + t) * 512 + n0 + wn + ni * 16 + lm] = acc[mi][ni][r];
      }
    }
  }
}

// ------------- G, M, C_v Gram reductions via MFMA (partials, no atomics) -------------
__global__ __launch_bounds__(256) void build_gmc_mfma_k(
    const float* __restrict__ Y1, const float* __restrict__ Y2,
    const int* __restrict__ pref,
    float* __restrict__ Gp, float* __restrict__ Mp, float* __restrict__ Cp) {
  int P = pref[0]; P = P < 1 ? 1 : (P > TT - 1 ? TT - 1 : P);
  const int c  = blockIdx.x;
  const int bh = blockIdx.y;
  const int b = bh >> 4, h = bh & 15;
  const int chunk = (P + TCH - 1) / TCH;
  const int tb = c * chunk;
  const int te = min(tb + chunk, P);

  __shared__ __align__(16) unsigned short kCh[32 * 136], kCl[32 * 136];
  __shared__ __align__(16) unsigned short kPh[32 * 136], kPl[32 * 136];
  __shared__ __align__(16) unsigned short vTh[64 * 136], vTl[64 * 136];

  const int tid = threadIdx.x;
  const int wid = tid >> 6, lane = tid & 63;
  const int lm = lane & 15, lq = lane >> 4;

  f4v acc[4];
#pragma unroll
  for (int i = 0; i < 4; i++) acc[i] = (f4v){0.f, 0.f, 0.f, 0.f};

  for (int t0 = tb; t0 < te; t0 += 128) {
    const int len = (te - t0 < 128) ? (te - t0) : 128;
    __syncthreads();
    // stage keys: rows 0..128 map t = t0-1+row; kC[u=row-1] current, kP[u=row] prev
    for (int e = tid; e < 129 * 8; e += 256) {
      int row = e >> 3, j4 = (e & 7) << 2;
      int t = t0 - 1 + row;
      float4 kv = make_float4(0.f, 0.f, 0.f, 0.f);
      if (row <= len && t >= 0)
        kv = *(const float4*)&Y1[((size_t)b * TT + t) * 512 + h * 32 + j4];
      unsigned short hh[4], ll[4];
      split_bf16(kv.x, hh[0], ll[0]); split_bf16(kv.y, hh[1], ll[1]);
      split_bf16(kv.z, hh[2], ll[2]); split_bf16(kv.w, hh[3], ll[3]);
      if (row >= 1) {
#pragma unroll
        for (int q = 0; q < 4; q++) {
          kCh[(j4 + q) * 136 + row - 1] = hh[q];
          kCl[(j4 + q) * 136 + row - 1] = ll[q];
        }
      }
      if (row < 128) {
#pragma unroll
        for (int q = 0; q < 4; q++) {
          kPh[(j4 + q) * 136 + row] = hh[q];
          kPl[(j4 + q) * 136 + row] = ll[q];
        }
      }
    }
    // stage values: v_t[d] at u = row
    for (int e = tid; e < 128 * 16; e += 256) {
      int row = e >> 4, dj = (e & 15) << 2;
      int t = t0 + row;
      float4 vv = make_float4(0.f, 0.f, 0.f, 0.f);
      if (row < len)
        vv = *(const float4*)&Y2[((size_t)b * P + t) * 1024 + h * 64 + dj];
      unsigned short hh[4], ll[4];
      split_bf16(vv.x, hh[0], ll[0]); split_bf16(vv.y, hh[1], ll[1]);
      split_bf16(vv.z, hh[2], ll[2]); split_bf16(vv.w, hh[3], ll[3]);
#pragma unroll
      for (int q = 0; q < 4; q++) {
        vTh[(dj + q) * 136 + row] = hh[q];
        vTl[(dj + q) * 136 + row] = ll[q];
      }
    }
    __syncthreads();

#pragma unroll
    for (int kk = 0; kk < 128; kk += 32) {
      const int off = kk + lq * 8;
      if (wid == 0) {
        s8v h0 = *(const s8v*)&kCh[(0 + lm) * 136 + off];
        s8v h1 = *(const s8v*)&kCh[(16 + lm) * 136 + off];
        s8v l0 = *(const s8v*)&kCl[(0 + lm) * 136 + off];
        s8v l1 = *(const s8v*)&kCl[(16 + lm) * 136 + off];
        acc[0] = __builtin_amdgcn_mfma_f32_16x16x32_bf16(h0, h0, acc[0], 0, 0, 0);
        acc[0] = __builtin_amdgcn_mfma_f32_16x16x32_bf16(h0, l0, acc[0], 0, 0, 0);
        acc[0] = __builtin_amdgcn_mfma_f32_16x16x32_bf16(l0, h0, acc[0], 0, 0, 0);
        acc[1] = __builtin_amdgcn_mfma_f32_16x16x32_bf16(h0, h1, acc[1], 0, 0, 0);
        acc[1] = __builtin_amdgcn_mfma_f32_16x16x32_bf16(h0, l1, acc[1], 0, 0, 0);
        acc[1] = __builtin_amdgcn_mfma_f32_16x16x32_bf16(l0, h1, acc[1], 0, 0, 0);
        acc[2] = __builtin_amdgcn_mfma_f32_16x16x32_bf16(h1, h0, acc[2], 0, 0, 0);
        acc[2] = __builtin_amdgcn_mfma_f32_16x16x32_bf16(h1, l0, acc[2], 0, 0, 0);
        acc[2] = __builtin_amdgcn_mfma_f32_16x16x32_bf16(l1, h0, acc[2], 0, 0, 0);
        acc[3] = __builtin_amdgcn_mfma_f32_16x16x32_bf16(h1, h1, acc[3], 0, 0, 0);
        acc[3] = __builtin_amdgcn_mfma_f32_16x16x32_bf16(h1, l1, acc[3], 0, 0, 0);
        acc[3] = __builtin_amdgcn_mfma_f32_16x16x32_bf16(l1, h1, acc[3], 0, 0, 0);
      } else if (wid == 1) {
        s8v ah0 = *(const s8v*)&kCh[(0 + lm) * 136 + off];
        s8v ah1 = *(const s8v*)&kCh[(16 + lm) * 136 + off];
        s8v al0 = *(const s8v*)&kCl[(0 + lm) * 136 + off];
        s8v al1 = *(const s8v*)&kCl[(16 + lm) * 136 + off];
        s8v bh0 = *(const s8v*)&kPh[(0 + lm) * 136 + off];
        s8v bh1 = *(const s8v*)&kPh[(16 + lm) * 136 + off];
        s8v bl0 = *(const s8v*)&kPl[(0 + lm) * 136 + off];
        s8v bl1 = *(const s8v*)&kPl[(16 + lm) * 136 + off];
        acc[0] = __builtin_amdgcn_mfma_f32_16x16x32_bf16(ah0, bh0, acc[0], 0, 0, 0);
        acc[0] = __builtin_amdgcn_mfma_f32_16x16x32_bf16(ah0, bl0, acc[0], 0, 0, 0);
        acc[0] = __builtin_amdgcn_mfma_f32_16x16x32_bf16(al0, bh0, acc[0], 0, 0, 0);
        acc[1] = __builtin_amdgcn_mfma_f32_16x16x32_bf16(ah0, bh1, acc[1], 0, 0, 0);
        acc[1] = __builtin_amdgcn_mfma_f32_16x16x32_bf16(ah0, bl1, acc[1], 0, 0, 0);
        acc[1] = __builtin_amdgcn_mfma_f32_16x16x32_bf16(al0, bh1, acc[1], 0, 0, 0);
        acc[2] = __builtin_amdgcn_mfma_f32_16x16x32_bf16(ah1, bh0, acc[2], 0, 0, 0);
        acc[2] = __builtin_amdgcn_mfma_f32_16x16x32_bf16(ah1, bl0, acc[2], 0, 0, 0);
        acc[2] = __builtin_amdgcn_mfma_f32_16x16x32_bf16(al1, bh0, acc[2], 0, 0, 0);
        acc[3] = __builtin_amdgcn_mfma_f32_16x16x32_bf16(ah1, bh1, acc[3], 0, 0, 0);
        acc[3] = __builtin_amdgcn_mfma_f32_16x16x32_bf16(ah1, bl1, acc[3], 0, 0, 0);
        acc[3] = __builtin_amdgcn_mfma_f32_16x16x32_bf16(al1, bh1, acc[3], 0, 0, 0);
      } else {
        const int d0 = (wid - 2) * 32;
        s8v vh0 = *(const s8v*)&vTh[(d0 + lm) * 136 + off];
        s8v vh1 = *(const s8v*)&vTh[(d0 + 16 + lm) * 136 + off];
        s8v vl0 = *(const s8v*)&vTl[(d0 + lm) * 136 + off];
        s8v vl1 = *(const s8v*)&vTl[(d0 + 16 + lm) * 136 + off];
        s8v kh0 = *(const s8v*)&kCh[(0 + lm) * 136 + off];
        s8v kh1 = *(const s8v*)&kCh[(16 + lm) * 136 + off];
        s8v kl0 = *(const s8v*)&kCl[(0 + lm) * 136 + off];
        s8v kl1 = *(const s8v*)&kCl[(16 + lm) * 136 + off];
        acc[0] = __builtin_amdgcn_mfma_f32_16x16x32_bf16(vh0, kh0, acc[0], 0, 0, 0);
        acc[0] = __builtin_amdgcn_mfma_f32_16x16x32_bf16(vh0, kl0, acc[0], 0, 0, 0);
        acc[0] = __builtin_amdgcn_mfma_f32_16x16x32_bf16(vl0, kh0, acc[0], 0, 0, 0);
        acc[1] = __builtin_amdgcn_mfma_f32_16x16x32_bf16(vh0, kh1, acc[1], 0, 0, 0);
        acc[1] = __builtin_amdgcn_mfma_f32_16x16x32_bf16(vh0, kl1, acc[1], 0, 0, 0);
        acc[1] = __builtin_amdgcn_mfma_f32_16x16x32_bf16(vl0, kh1, acc[1], 0, 0, 0);
        acc[2] = __builtin_amdgcn_mfma_f32_16x16x32_bf16(vh1, kh0, acc[2], 0, 0, 0);
        acc[2] = __builtin_amdgcn_mfma_f32_16x16x32_bf16(vh1, kl0, acc[2], 0, 0, 0);
        acc[2] = __builtin_amdgcn_mfma_f32_16x16x32_bf16(vl1, kh0, acc[2], 0, 0, 0);
        acc[3] = __builtin_amdgcn_mfma_f32_16x16x32_bf16(vh1, kh1, acc[3], 0, 0, 0);
        acc[3] = __builtin_amdgcn_mfma_f32_16x16x32_bf16(vh1, kl1, acc[3], 0, 0, 0);
        acc[3] = __builtin_amdgcn_mfma_f32_16x16x32_bf16(vl1, kh1, acc[3], 0, 0, 0);
      }
    }
  }

  // write partials (D layout: col = lm, row = lq*4 + r)
  if (wid < 2) {
    float* dst = (wid == 0 ? Gp : Mp) + (size_t)(c * 64 + bh) * 1024;
#pragma unroll
    for (int t = 0; t < 4; t++) {
      int i0 = (t >> 1) * 16, j0 = (t & 1) * 16;
#pragma unroll
      for (int r = 0; r < 4; r++)
        dst[(i0 + lq * 4 + r) * 32 + j0 + lm] = acc[t][r];
    }
  } else {
    float* dst = Cp + (size_t)(c * 64 + bh) * 2048;
#pragma unroll
    for (int t = 0; t < 4; t++) {
      int d0 = (wid - 2) * 32 + (t >> 1) * 16, j0 = (t & 1) * 16;
#pragma unroll
      for (int r = 0; r < 4; r++)
        dst[(d0 + lq * 4 + r) * 32 + j0 + lm] = acc[t][r];
    }
  }
}

// ------- per-(b,h) operator: chol, G^{-1}, A_w, sigma, F = Cv*Gi*(s*M*Gi)^4 -------
__global__ __launch_bounds__(256) void solve_op_k(
    const float* __restrict__ Gp, const float* __restrict__ Mp,
    const float* __restrict__ Cp, const float* __restrict__ lridge,
    const float* __restrict__ lgamma, float* __restrict__ Ft) {
  __shared__ float Gs[32 * 33];
  __shared__ float Ms[32 * 32];
  __shared__ float Gi[32 * 32];
  __shared__ float W1[32 * 33];
  __shared__ float Aw[32 * 33];
  __shared__ float Nn[32 * 32];
  __shared__ float N2[32 * 32];
  __shared__ float T1[32 * 32];
  __shared__ float Cs[64 * 32];
  __shared__ float red[256];
  __shared__ float vv[32], uu[32];
  const int bh = blockIdx.x;
  const int tid = threadIdx.x;
  const float ridge = expf(lridge[0]);

  for (int e = tid; e < 1024; e += 256) {
    int i = e >> 5, j = e & 31;
    float g = 0.f, m = 0.f;
#pragma unroll
    for (int cc = 0; cc < TCH; cc++) {
      g += Gp[(size_t)(cc * 64 + bh) * 1024 + e];
      m += Mp[(size_t)(cc * 64 + bh) * 1024 + e];
    }
    if (i == j) g += ridge;
    Gs[i * 33 + j] = g;
    Ms[e] = m;
  }
  for (int e = tid; e < 2048; e += 256) {
    float s = 0.f;
#pragma unroll
    for (int cc = 0; cc < TCH; cc++) s += Cp[(size_t)(cc * 64 + bh) * 2048 + e];
    Cs[e] = s;
  }
  __syncthreads();

  for (int j = 0; j < 32; j++) {
    float d = Gs[j * 33 + j];
    __syncthreads();
    float inv = 1.0f / sqrtf(d);
    if (tid >= j && tid < 32) Gs[tid * 33 + j] *= inv;
    __syncthreads();
    int w = 31 - j;
    for (int e = tid; e < w * w; e += 256) {
      int i = j + 1 + e / w, k = j + 1 + e % w;
      Gs[i * 33 + k] -= Gs[i * 33 + j] * Gs[k * 33 + j];
    }
    __syncthreads();
  }

  if (tid < 32) {
    const int c = tid;
    for (int i = 0; i < 32; i++) W1[i * 33 + c] = (i == c) ? 1.0f : 0.0f;
    for (int i = 0; i < 32; i++) {
      float s = W1[i * 33 + c];
      for (int j = 0; j < i; j++) s -= Gs[i * 33 + j] * W1[j * 33 + c];
      W1[i * 33 + c] = s / Gs[i * 33 + i];
    }
    for (int i = 31; i >= 0; i--) {
      float s = W1[i * 33 + c];
      for (int j = i + 1; j < 32; j++) s -= Gs[j * 33 + i] * W1[j * 33 + c];
      W1[i * 33 + c] = s / Gs[i * 33 + i];
    }
    for (int i = 0; i < 32; i++) Gi[i * 32 + c] = W1[i * 33 + c];
  }
  __syncthreads();
  if (tid < 32) {
    const int c = tid;
    for (int i = 0; i < 32; i++) {
      float s = Ms[i * 32 + c];
      for (int j = 0; j < i; j++) s -= Gs[i * 33 + j] * W1[j * 33 + c];
      W1[i * 33 + c] = s / Gs[i * 33 + i];
    }
  }
  __syncthreads();
  if (tid < 32) {
    const int c = tid;
    for (int i = 0; i < 32; i++) {
      float s = W1[c * 33 + i];
      for (int j = 0; j < i; j++) s -= Gs[i * 33 + j] * Aw[j * 33 + c];
      Aw[i * 33 + c] = s / Gs[i * 33 + i];
    }
  }
  __syncthreads();

  float s0 = 0.0f;
  for (int e = tid; e < 1024; e += 256) {
    float a = Aw[(e >> 5) * 33 + (e & 31)];
    s0 += a * a;
  }
  red[tid] = s0;
  __syncthreads();
  for (int off = 128; off > 0; off >>= 1) {
    if (tid < off) red[tid] += red[tid + off];
    __syncthreads();
  }
  float frob2 = red[0];
  float sigma;
  if (frob2 <= 1.0f) {
    sigma = sqrtf(frob2);
  } else {
    if (tid < 32) vv[tid] = 1.0f + 0.001f * (float)tid;
    __syncthreads();
    for (int it = 0; it < 64; it++) {
      if (tid < 32) {
        float s = 0;
        for (int j = 0; j < 32; j++) s += Aw[tid * 33 + j] * vv[j];
        uu[tid] = s;
      }
      __syncthreads();
      if (tid == 0) {
        float n = 0;
        for (int j = 0; j < 32; j++) n += uu[j] * uu[j];
        red[0] = sqrtf(n);
      }
      __syncthreads();
      float nu = fmaxf(red[0], 1e-30f);
      if (tid < 32) uu[tid] /= nu;
      __syncthreads();
      if (tid < 32) {
        float s = 0;
        for (int j = 0; j < 32; j++) s += Aw[j * 33 + tid] * uu[j];
        vv[tid] = s;
      }
      __syncthreads();
      if (tid == 0) {
        float n = 0;
        for (int j = 0; j < 32; j++) n += vv[j] * vv[j];
        red[0] = sqrtf(n);
      }
      __syncthreads();
      float nv = fmaxf(red[0], 1e-30f);
      if (tid < 32) vv[tid] /= nv;
      __syncthreads();
    }
    sigma = red[0];
  }
  float gamma_c = fminf(expf(lgamma[0]), 1.0f);
  float scale = gamma_c / fmaxf(fmaxf(sigma, 1e-8f), 1.0f);

  for (int e = tid; e < 1024; e += 256) {
    int i = e >> 5, c = e & 31;
    float s = 0;
#pragma unroll
    for (int k = 0; k < 32; k++) s += Ms[i * 32 + k] * Gi[k * 32 + c];
    Nn[e] = scale * s;
  }
  __syncthreads();
  for (int e = tid; e < 1024; e += 256) {
    int i = e >> 5, c = e & 31;
    float s = 0;
#pragma unroll
    for (int k = 0; k < 32; k++) s += Nn[i * 32 + k] * Nn[k * 32 + c];
    N2[e] = s;
  }
  __syncthreads();
  for (int e = tid; e < 1024; e += 256) {
    int i = e >> 5, c = e & 31;
    float s = 0;
#pragma unroll
    for (int k = 0; k < 32; k++) s += N2[i * 32 + k] * N2[k * 32 + c];
    Ms[e] = s;
  }
  __syncthreads();
  for (int e = tid; e < 1024; e += 256) {
    int i = e >> 5, c = e & 31;
    float s = 0;
#pragma unroll
    for (int k = 0; k < 32; k++) s += Gi[i * 32 + k] * Ms[k * 32 + c];
    T1[e] = s;
  }
  __syncthreads();
  for (int e = tid; e < 2048; e += 256) {
    int j = e >> 6, d = e & 63;
    float s = 0;
#pragma unroll
    for (int k = 0; k < 32; k++) s += Cs[d * 32 + k] * T1[k * 32 + j];
    Ft[(size_t)bh * 2048 + e] = s;
  }
}

// ------------- apply F^T per (head, 128-token chunk) -> full_hi (bf16) -------------
// FH written chunk-swizzled within each head's 64-col group (gemm_out consumes).
__global__ __launch_bounds__(256) void apply_k(const float* __restrict__ Y1,
                                               const float* __restrict__ Ft,
                                               unsigned short* __restrict__ FH) {
  __shared__ float xs[128 * 32];
  const int h = blockIdx.y;
  const int r0 = blockIdx.x * 128;
  const int bh = (r0 >> 12) * NH + h;
  const int tid = threadIdx.x;
  const int d = tid & 63, t0 = tid >> 6;
  float fcol[32];
  const float* fb = &Ft[(size_t)bh * 2048 + d];
#pragma unroll
  for (int j = 0; j < 32; j++) fcol[j] = fb[j * 64];
  for (int e = tid; e < 1024; e += 256) {
    int row = e >> 3, j4 = (e & 7) << 2;
    *(float4*)&xs[row * 32 + j4] =
        *(const float4*)&Y1[((size_t)(r0 + row)) * 512 + h * 32 + j4];
  }
  __syncthreads();
  const int dq = d >> 3, dr = d & 7;
  for (int tl = t0; tl < 128; tl += 4) {
    float s = 0;
#pragma unroll
    for (int j = 0; j < 32; j++) s += xs[tl * 32 + j] * fcol[j];
    int col = h * 64 + ((dq ^ (tl & 7)) << 3) + dr;
    FH[((size_t)(r0 + tl)) * 1024 + col] = bf16_rne(s);
  }
}

// ------------- output GEMM (MFMA): out = sg * full @ Wo ; A=hi, B=hi+lo -------------
// 256x128 tile, BK=64, 8 waves, double-buffered LDS, counted vmcnt (never 0 in
// steady state), pre-swizzled-global + swizzled ds_read (bank-floor reads).
__global__ __launch_bounds__(512) void gemm_out_k(
    const unsigned short* __restrict__ FH,
    const unsigned short* __restrict__ WThi, const unsigned short* __restrict__ WTlo,
    const float* __restrict__ alpha, float* __restrict__ out) {
  __shared__ __align__(16) unsigned short lds[65536];  // 128 KB: A 2x32K, Bh 2x16K, Bl 2x16K
  int xx, yy, zz;
  xcd_swz(8, 64, xx, yy, zz);
  const int m0 = yy * 256;
  const int n0 = xx * 128;
  const int tid = threadIdx.x;
  const int lane = tid & 63;
  const int wid  = tid >> 6;                 // 0..7
  const int wm = (wid >> 1) * 64;            // 4 M-waves x 64 rows
  const int wn = (wid & 1) * 64;             // 2 N-waves x 64 cols
  const int lm = lane & 15, lq = lane >> 4;
  const int l8 = lane >> 3, c8 = (lane & 7) << 3;  // staging: 8 rows x 8 chunks per issue

  f4v acc[4][4];
#pragma unroll
  for (int i = 0; i < 4; i++)
#pragma unroll
    for (int j = 0; j < 4; j++) acc[i][j] = (f4v){0.f, 0.f, 0.f, 0.f};

  auto STAGE = [&](int t, int buf) {
    const int kt = t * 64;
#pragma unroll
    for (int i = 0; i < 4; i++) {            // A: 4 issues/wave (32 total)
      int iss = wid * 4 + i;
      gll16(&lds[buf * 16384 + iss * 512],
            &FH[(size_t)(m0 + iss * 8 + l8) * 1024 + kt + c8]);
    }
#pragma unroll
    for (int i = 0; i < 2; i++) {            // Bh: 2 issues/wave (16 total)
      int iss = wid * 2 + i;
      gll16(&lds[32768 + buf * 8192 + iss * 512],
            &WThi[(size_t)(n0 + iss * 8 + l8) * 1024 + kt + c8]);
    }
#pragma unroll
    for (int i = 0; i < 2; i++) {            // Bl
      int iss = wid * 2 + i;
      gll16(&lds[49152 + buf * 8192 + iss * 512],
            &WTlo[(size_t)(n0 + iss * 8 + l8) * 1024 + kt + c8]);
    }
  };

  STAGE(0, 0);
  STAGE(1, 1);

  for (int t = 0; t < 16; t++) {
    const int buf = t & 1;
    if (t < 15) asm volatile("s_waitcnt vmcnt(8)" ::: "memory");
    else        asm volatile("s_waitcnt vmcnt(0)" ::: "memory");
    __builtin_amdgcn_s_barrier();
    const unsigned short* Ab  = &lds[buf * 16384];
    const unsigned short* Bhb = &lds[32768 + buf * 8192];
    const unsigned short* Blb = &lds[49152 + buf * 8192];
    __builtin_amdgcn_s_setprio(1);
#pragma unroll
    for (int kk = 0; kk < 2; kk++) {
      s8v ah[4], bh[4], bl[4];
#pragma unroll
      for (int i = 0; i < 4; i++) {
        int rA = wm + i * 16 + lm;
        int rB = wn + i * 16 + lm;
        int sA = (((kk * 4 + lq) ^ (rA & 7)) << 3);
        int sB = (((kk * 4 + lq) ^ (rB & 7)) << 3);
        ah[i] = *(const s8v*)&Ab[rA * 64 + sA];
        bh[i] = *(const s8v*)&Bhb[rB * 64 + sB];
        bl[i] = *(const s8v*)&Blb[rB * 64 + sB];
      }
#pragma unroll
      for (int mi = 0; mi < 4; mi++)
#pragma unroll
        for (int ni = 0; ni < 4; ni++) {
          acc[mi][ni] = __builtin_amdgcn_mfma_f32_16x16x32_bf16(ah[mi], bh[ni], acc[mi][ni], 0, 0, 0);
          acc[mi][ni] = __builtin_amdgcn_mfma_f32_16x16x32_bf16(ah[mi], bl[ni], acc[mi][ni], 0, 0, 0);
        }
    }
    __builtin_amdgcn_s_setprio(0);
    __builtin_amdgcn_sched_barrier(0);
    __builtin_amdgcn_s_barrier();
    if (t < 14) STAGE(t + 2, buf);
  }

  float sg = 1.0f / (1.0f + expf(-alpha[0]));
#pragma unroll
  for (int mi = 0; mi < 4; mi++)
#pragma unroll
    for (int r = 0; r < 4; r++) {
      size_t orow = (size_t)(m0 + wm + mi * 16 + lq * 4 + r);
#pragma unroll
      for (int ni = 0; ni < 4; ni++)
        out[orow * 1024 + n0 + wn + ni * 16 + lm] = sg * acc[mi][ni][r];
    }
}

extern "C" void kernel_launch(void* const* d_in, const int* in_sizes, int n_in,
                              void* d_out, int out_size, void* d_ws, size_t ws_size,
                              hipStream_t stream) {
  const float* X      = (const float*)d_in[0];
  const float* Wk     = (const float*)d_in[1];
  const float* Wq     = (const float*)d_in[2];
  const float* Wv     = (const float*)d_in[3];
  const float* Wo     = (const float*)d_in[4];
  const float* lng    = (const float*)d_in[5];
  const float* lnb    = (const float*)d_in[6];
  const float* alpha  = (const float*)d_in[7];
  const float* lridge = (const float*)d_in[8];
  const float* lgamma = (const float*)d_in[9];
  const int*   pref   = (const int*)d_in[10];
  float* out = (float*)d_out;
  char* ws = (char*)d_ws;
  float* stats = (float*)(ws + OFF_STATS);
  float* Gp    = (float*)(ws + OFF_GP);
  float* Mp    = (float*)(ws + OFF_MP);
  float* Cp    = (float*)(ws + OFF_CP);
  float* Ft    = (float*)(ws + OFF_FT);
  unsigned short* WKH = (unsigned short*)(ws + OFF_WKH);
  unsigned short* WKL = (unsigned short*)(ws + OFF_WKL);
  unsigned short* WQH = (unsigned short*)(ws + OFF_WQH);
  unsigned short* WQL = (unsigned short*)(ws + OFF_WQL);
  unsigned short* WVH = (unsigned short*)(ws + OFF_WVH);
  unsigned short* WVL = (unsigned short*)(ws + OFF_WVL);
  unsigned short* WOH = (unsigned short*)(ws + OFF_WOH);
  unsigned short* WOL = (unsigned short*)(ws + OFF_WOL);
  float* Y1 = (float*)(ws + OFF_Y1);
  float* Y2 = (float*)(ws + OFF_Y2);
  unsigned short* FH = (unsigned short*)(ws + OFF_FH);

  ln_stats_k<<<16384, 256, 0, stream>>>(X, stats);
  prep_w_k<<<dim3(16, 32), 256, 0, stream>>>(Wk, 512, WKH, WKL, 0);
  prep_w_k<<<dim3(16, 32), 256, 0, stream>>>(Wq, 512, WQH, WQL, 0);
  prep_w_k<<<dim3(32, 32), 256, 0, stream>>>(Wv, 1024, WVH, WVL, 0);
  prep_w_k<<<dim3(32, 32), 256, 0, stream>>>(Wo, 1024, WOH, WOL, 1);
  gemm_kq_k<<<dim3(4, 32, NB), 256, 0, stream>>>(X, stats, lng, lnb, WKH, WKL, WQH, WQL, pref, Y1);
  gemm_proj_k<<<dim3(8, 32, NB), 256, 0, stream>>>(X, stats, lng, lnb, WVH, WVL, 1024, pref, 2, Y2);
  build_gmc_mfma_k<<<dim3(TCH, 64), 256, 0, stream>>>(Y1, Y2, pref, Gp, Mp, Cp);
  solve_op_k<<<64, 256, 0, stream>>>(Gp, Mp, Cp, lridge, lgamma, Ft);
  apply_k<<<dim3(128, NH), 256, 0, stream>>>(Y1, Ft, FH);
  gemm_out_k<<<dim3(8, 64), 512, 0, stream>>>(FH, WOH, WOL, alpha, out);
}